// Round 1
// baseline (16509.171 us; speedup 1.0000x reference)
//
#include <hip/hip_runtime.h>

#define N_ROWS 65536
#define IN_DIM 1024
#define HID    2048
#define EMB    256
#define NCODE  4096

// ---------------- prep: codebook transpose + 0.5*||c||^2 ----------------
__global__ void k_prep(const float* __restrict__ cb, float* __restrict__ cbT,
                       float* __restrict__ halfsq) {
    const int k = blockIdx.x * 256 + threadIdx.x;   // code id
    const float* row = cb + (size_t)k * EMB;
    float s = 0.f;
    for (int e = 0; e < EMB; ++e) {
        const float v = row[e];
        cbT[(size_t)e * NCODE + k] = v;             // coalesced in k
        s = fmaf(v, v, s);
    }
    halfsq[k] = 0.5f * s;
}

// ---------------- encoder: enc = relu(x@W1+b1)@W2 + b2 ----------------
// block: 16 rows, 256 threads. Thread t owns hidden col (chunk) / enc col t.
__global__ __launch_bounds__(256) void k_encoder(
    const float* __restrict__ x, const float* __restrict__ W1,
    const float* __restrict__ b1, const float* __restrict__ W2,
    const float* __restrict__ b2, float* __restrict__ enc) {
    __shared__ float s_x[16][IN_DIM];   // 64 KB
    __shared__ float s_h[16][256];      // 16 KB
    const int t = threadIdx.x;
    const int row0 = blockIdx.x * 16;

    // stage x rows (coalesced float4)
    const float4* xg = reinterpret_cast<const float4*>(x + (size_t)row0 * IN_DIM);
    float4* xs = reinterpret_cast<float4*>(&s_x[0][0]);
    for (int i = t; i < 16 * IN_DIM / 4; i += 256) xs[i] = xg[i];
    __syncthreads();

    float acc2[16];
    const float bb2 = b2[t];
    #pragma unroll
    for (int r = 0; r < 16; ++r) acc2[r] = bb2;

    for (int c = 0; c < 8; ++c) {                 // 8 hidden chunks of 256
        const int hc0 = c << 8;
        const int j = hc0 + t;                    // owned hidden col
        float acc1[16];
        #pragma unroll
        for (int r = 0; r < 16; ++r) acc1[r] = 0.f;
        const float* w1p = W1 + j;
        for (int k = 0; k < IN_DIM; k += 4) {
            const float w0 = w1p[(size_t)(k + 0) * HID];
            const float w1v = w1p[(size_t)(k + 1) * HID];
            const float w2v = w1p[(size_t)(k + 2) * HID];
            const float w3v = w1p[(size_t)(k + 3) * HID];
            #pragma unroll
            for (int r = 0; r < 16; ++r) {
                const float4 xv = *reinterpret_cast<const float4*>(&s_x[r][k]);
                acc1[r] = fmaf(xv.x, w0, acc1[r]);
                acc1[r] = fmaf(xv.y, w1v, acc1[r]);
                acc1[r] = fmaf(xv.z, w2v, acc1[r]);
                acc1[r] = fmaf(xv.w, w3v, acc1[r]);
            }
        }
        const float bb1 = b1[j];
        #pragma unroll
        for (int r = 0; r < 16; ++r) s_h[r][t] = fmaxf(acc1[r] + bb1, 0.f);
        __syncthreads();
        const float* w2pp = W2 + (size_t)hc0 * EMB + t;
        for (int k = 0; k < 256; k += 4) {
            const float wa = w2pp[(size_t)(k + 0) * EMB];
            const float wb = w2pp[(size_t)(k + 1) * EMB];
            const float wc = w2pp[(size_t)(k + 2) * EMB];
            const float wd = w2pp[(size_t)(k + 3) * EMB];
            #pragma unroll
            for (int r = 0; r < 16; ++r) {
                const float4 hv = *reinterpret_cast<const float4*>(&s_h[r][k]);
                acc2[r] = fmaf(hv.x, wa, acc2[r]);
                acc2[r] = fmaf(hv.y, wb, acc2[r]);
                acc2[r] = fmaf(hv.z, wc, acc2[r]);
                acc2[r] = fmaf(hv.w, wd, acc2[r]);
            }
        }
        __syncthreads();   // protect s_h before next chunk rewrites it
    }
    for (int r = 0; r < 16; ++r) enc[(size_t)(row0 + r) * EMB + t] = acc2[r];
}

// ---------------- argmin over codes: argmax(e.c - 0.5||c||^2) ----------------
__global__ __launch_bounds__(256) void k_argmin(
    const float* __restrict__ enc, const float* __restrict__ cbT,
    const float* __restrict__ halfsq, int* __restrict__ idx) {
    __shared__ float s_e[16][EMB];      // 16 KB
    __shared__ float s_rs[4][16];
    __shared__ int   s_ri[4][16];
    const int t = threadIdx.x;
    const int row0 = blockIdx.x * 16;
    for (int r = 0; r < 16; ++r) s_e[r][t] = enc[(size_t)(row0 + r) * EMB + t];
    __syncthreads();

    float best[16]; int bidx[16];
    #pragma unroll
    for (int r = 0; r < 16; ++r) { best[r] = -1e30f; bidx[r] = 0; }

    for (int kc = 0; kc < NCODE; kc += 256) {
        const int ccode = kc + t;                 // owned code
        float acc[16];
        #pragma unroll
        for (int r = 0; r < 16; ++r) acc[r] = 0.f;
        const float* cp = cbT + ccode;
        for (int e = 0; e < EMB; e += 4) {
            const float c0 = cp[(size_t)(e + 0) * NCODE];
            const float c1 = cp[(size_t)(e + 1) * NCODE];
            const float c2 = cp[(size_t)(e + 2) * NCODE];
            const float c3 = cp[(size_t)(e + 3) * NCODE];
            #pragma unroll
            for (int r = 0; r < 16; ++r) {
                const float4 ev = *reinterpret_cast<const float4*>(&s_e[r][e]);
                acc[r] = fmaf(ev.x, c0, acc[r]);
                acc[r] = fmaf(ev.y, c1, acc[r]);
                acc[r] = fmaf(ev.z, c2, acc[r]);
                acc[r] = fmaf(ev.w, c3, acc[r]);
            }
        }
        const float hs = halfsq[ccode];
        #pragma unroll
        for (int r = 0; r < 16; ++r) {
            const float s = acc[r] - hs;
            if (s > best[r]) { best[r] = s; bidx[r] = ccode; }  // strict >: first (lowest) code wins
        }
    }
    // cross-lane / cross-wave argmax with lowest-index tie-break
    const int lane = t & 63, wid = t >> 6;
    #pragma unroll
    for (int r = 0; r < 16; ++r) {
        float s = best[r]; int i = bidx[r];
        for (int off = 32; off > 0; off >>= 1) {
            const float os = __shfl_down(s, off);
            const int   oi = __shfl_down(i, off);
            if (os > s || (os == s && oi < i)) { s = os; i = oi; }
        }
        if (lane == 0) { s_rs[wid][r] = s; s_ri[wid][r] = i; }
    }
    __syncthreads();
    if (t < 16) {
        float s = s_rs[0][t]; int i = s_ri[0][t];
        for (int w = 1; w < 4; ++w) {
            const float os = s_rs[w][t]; const int oi = s_ri[w][t];
            if (os > s || (os == s && oi < i)) { s = os; i = oi; }
        }
        idx[row0 + t] = i;
    }
}

// ---------------- decoder: q=cb[idx]; dec = relu(q@W3+b3)@W4 + b4 ----------------
__global__ __launch_bounds__(256) void k_decoder(
    const int* __restrict__ idx, const float* __restrict__ cb,
    const float* __restrict__ W3, const float* __restrict__ b3,
    const float* __restrict__ W4, const float* __restrict__ b4,
    float* __restrict__ outq, float* __restrict__ outd) {
    __shared__ float s_q[8][EMB];       // 8 KB
    __shared__ float s_h2[8][HID];      // 64 KB
    __shared__ int s_ix[8];
    const int t = threadIdx.x;
    const int row0 = blockIdx.x * 8;
    if (t < 8) s_ix[t] = idx[row0 + t];
    __syncthreads();
    #pragma unroll
    for (int r = 0; r < 8; ++r) {
        const float v = cb[(size_t)s_ix[r] * EMB + t];
        s_q[r][t] = v;
        outq[(size_t)(row0 + r) * EMB + t] = v;     // quantized output (exact)
    }
    __syncthreads();
    // GEMM3: h2 = relu(q@W3 + b3), thread owns 8 hidden cols (one per group)
    for (int g = 0; g < 8; ++g) {
        const int j = (g << 8) + t;
        float acc[8];
        #pragma unroll
        for (int r = 0; r < 8; ++r) acc[r] = 0.f;
        const float* wp = W3 + j;
        for (int e = 0; e < EMB; e += 4) {
            const float w0 = wp[(size_t)(e + 0) * HID];
            const float w1v = wp[(size_t)(e + 1) * HID];
            const float w2v = wp[(size_t)(e + 2) * HID];
            const float w3v = wp[(size_t)(e + 3) * HID];
            #pragma unroll
            for (int r = 0; r < 8; ++r) {
                const float4 qv = *reinterpret_cast<const float4*>(&s_q[r][e]);
                acc[r] = fmaf(qv.x, w0, acc[r]);
                acc[r] = fmaf(qv.y, w1v, acc[r]);
                acc[r] = fmaf(qv.z, w2v, acc[r]);
                acc[r] = fmaf(qv.w, w3v, acc[r]);
            }
        }
        const float bb = b3[j];
        #pragma unroll
        for (int r = 0; r < 8; ++r) s_h2[r][j] = fmaxf(acc[r] + bb, 0.f);
    }
    __syncthreads();
    // GEMM4: thread owns 4 output cols {t, 256+t, 512+t, 768+t} x 8 rows
    float acc4[8][4];
    #pragma unroll
    for (int r = 0; r < 8; ++r)
        #pragma unroll
        for (int ci = 0; ci < 4; ++ci) acc4[r][ci] = 0.f;
    const float* w4p = W4 + t;
    for (int k = 0; k < HID; k += 4) {
        float wv[4][4];
        #pragma unroll
        for (int ki = 0; ki < 4; ++ki)
            #pragma unroll
            for (int ci = 0; ci < 4; ++ci)
                wv[ki][ci] = w4p[(size_t)(k + ki) * IN_DIM + (ci << 8)];
        #pragma unroll
        for (int r = 0; r < 8; ++r) {
            const float4 hv = *reinterpret_cast<const float4*>(&s_h2[r][k]);
            #pragma unroll
            for (int ci = 0; ci < 4; ++ci) {
                acc4[r][ci] = fmaf(hv.x, wv[0][ci], acc4[r][ci]);
                acc4[r][ci] = fmaf(hv.y, wv[1][ci], acc4[r][ci]);
                acc4[r][ci] = fmaf(hv.z, wv[2][ci], acc4[r][ci]);
                acc4[r][ci] = fmaf(hv.w, wv[3][ci], acc4[r][ci]);
            }
        }
    }
    #pragma unroll
    for (int ci = 0; ci < 4; ++ci) {
        const float bb = b4[(ci << 8) + t];
        #pragma unroll
        for (int r = 0; r < 8; ++r)
            outd[(size_t)(row0 + r) * IN_DIM + (ci << 8) + t] = acc4[r][ci] + bb;
    }
}

extern "C" void kernel_launch(void* const* d_in, const int* in_sizes, int n_in,
                              void* d_out, int out_size, void* d_ws, size_t ws_size,
                              hipStream_t stream) {
    const float* x  = (const float*)d_in[0];
    const float* W1 = (const float*)d_in[1];
    const float* b1 = (const float*)d_in[2];
    const float* W2 = (const float*)d_in[3];
    const float* b2 = (const float*)d_in[4];
    const float* cb = (const float*)d_in[5];
    const float* W3 = (const float*)d_in[6];
    const float* b3 = (const float*)d_in[7];
    const float* W4 = (const float*)d_in[8];
    const float* b4 = (const float*)d_in[9];

    float* outq = (float*)d_out;                         // [N,256]
    float* outd = outq + (size_t)N_ROWS * EMB;           // [N,1024]

    // Scratch staging (all consumed before the decoder overwrites them):
    //  - cbT + halfsq live in the decoded-output region (written by k_prep,
    //    read only by k_argmin; k_decoder overwrites afterwards).
    //  - encoded lives in the quantized-output region (written by k_encoder,
    //    read only by k_argmin; k_decoder overwrites with the real quantized).
    //  - indices (256 KB) live in d_ws.
    float* cbT    = outd;                  // 256*4096 floats = 4 MB
    float* halfsq = outd + (size_t)EMB * NCODE;  // 4096 floats
    float* enc    = outq;                  // N*256 floats
    int*   idx    = (int*)d_ws;            // N ints = 256 KB

    k_prep   <<<NCODE / 256, 256, 0, stream>>>(cb, cbT, halfsq);
    k_encoder<<<N_ROWS / 16, 256, 0, stream>>>(x, W1, b1, W2, b2, enc);
    k_argmin <<<N_ROWS / 16, 256, 0, stream>>>(enc, cbT, halfsq, idx);
    k_decoder<<<N_ROWS / 8, 256, 0, stream>>>(idx, cb, W3, b3, W4, b4, outq, outd);
}

// Round 2
// 7925.859 us; speedup vs baseline: 2.0830x; 2.0830x over previous
//
#include <hip/hip_runtime.h>

#define N_ROWS 65536
#define IN_DIM 1024
#define HID    2048
#define EMB    256
#define NCODE  4096

typedef __attribute__((ext_vector_type(8))) short bf16x8;
typedef __attribute__((ext_vector_type(4))) float f32x4;

__device__ __forceinline__ unsigned short f2bf(float v) {
    unsigned u = __float_as_uint(v);
    u += 0x7FFFu + ((u >> 16) & 1u);
    return (unsigned short)(u >> 16);
}
__device__ __forceinline__ float bf2f(unsigned short h) {
    return __uint_as_float(((unsigned)h) << 16);
}

// ---------- weight pre-convert (+transpose) into tiled fragment layout ----------
// src: [K][NC] fp32 row-major. dst: tiles (nt,kt) of 16 cols x 64 k, elem (rr,k):
//   tile*1024 + ((k>>3)&7)*128 + rr*8 + (k&7)
template<int SPLIT>
__global__ __launch_bounds__(256) void k_conv_w(
    const float* __restrict__ src, unsigned short* __restrict__ dh,
    unsigned short* __restrict__ dl, int NC, int nkt)
{
    const int t = threadIdx.x;
    const int nt = blockIdx.x, kt = blockIdx.y;
    const int kk = t >> 2, j4 = (t & 3) << 2;
    const int k0 = kt << 6, n0 = nt << 4;
    float4 v = *(const float4*)(src + (size_t)(k0 + kk) * NC + n0 + j4);
    size_t tb = ((size_t)nt * nkt + kt) * 1024 + ((kk >> 3) * 128) + (kk & 7);
    float vv[4] = {v.x, v.y, v.z, v.w};
    #pragma unroll
    for (int j = 0; j < 4; ++j) {
        unsigned short h = f2bf(vv[j]);
        dh[tb + (size_t)(j4 + j) * 8] = h;
        if (SPLIT) dl[tb + (size_t)(j4 + j) * 8] = f2bf(vv[j] - bf2f(h));
    }
}

// ---------- codebook convert (tiled bf16, no transpose) + 0.5*||c||^2 ----------
__global__ __launch_bounds__(256) void k_conv_cb(
    const float* __restrict__ cb, unsigned short* __restrict__ ch,
    float* __restrict__ halfsq)
{
    const int t = threadIdx.x;
    const int ct = blockIdx.x;
    const int cl = t >> 4, f = t & 15;
    const int code = (ct << 4) + cl;
    float ssq = 0.f;
    #pragma unroll
    for (int it = 0; it < 4; ++it) {
        const int k4 = (f << 2) + (it << 6);
        float4 v = *(const float4*)(cb + (size_t)code * EMB + k4);
        ssq += v.x * v.x + v.y * v.y + v.z * v.z + v.w * v.w;
        size_t tb = ((size_t)(ct * 4 + (k4 >> 6))) * 1024 + ((k4 >> 3) & 7) * 128 + cl * 8 + (k4 & 7);
        ushort4 h = { f2bf(v.x), f2bf(v.y), f2bf(v.z), f2bf(v.w) };
        *(ushort4*)&ch[tb] = h;
    }
    #pragma unroll
    for (int off = 1; off <= 8; off <<= 1) ssq += __shfl_xor(ssq, off);
    if (f == 0) halfsq[code] = 0.5f * ssq;
}

// ---------- generic MFMA layer: out = [relu](A @ B + bias)  (split-bf16 optional) ----------
// BM=128, BN=128, KT=64. A: fp32 global, converted in-kernel (hi/lo if SPLIT).
// B: pre-tiled bf16 global (hi/lo if SPLIT). out: fp32 (init or accumulate).
template<int SPLIT>
__global__ __launch_bounds__(256) void k_layer(
    const float* __restrict__ A, int lda, int K,
    const unsigned short* __restrict__ Bh, const unsigned short* __restrict__ Bl,
    int b_nkt, const float* __restrict__ bias, int biasoff,
    float* __restrict__ out, int outw, int relu, int init)
{
    constexpr int AL = 8192;
    constexpr int BH = SPLIT ? 16384 : 8192;
    constexpr int BL = SPLIT ? 24576 : 8192;   // unused when !SPLIT
    __shared__ __align__(16) unsigned short s_mem[SPLIT ? 32768 : 16384];

    const int t = threadIdx.x;
    const int m0 = blockIdx.x * 128;
    const int nb0 = blockIdx.y * 128;
    const int lane = t & 63, wv = t >> 6;
    const int wm = wv >> 1, wn = wv & 1;
    const int g = lane >> 4, rr = lane & 15;

    f32x4 acc[4][4];
    #pragma unroll
    for (int mi = 0; mi < 4; ++mi)
        #pragma unroll
        for (int ni = 0; ni < 4; ++ni) acc[mi][ni] = (f32x4){0.f, 0.f, 0.f, 0.f};

    for (int kc = 0; kc < K; kc += 64) {
        // ---- stage A (convert fp32 -> hi/lo bf16, XOR-swizzled fragment layout)
        #pragma unroll
        for (int it = 0; it < 8; ++it) {
            int f = t + (it << 8);
            int r = f >> 4, k4 = (f & 15) << 2;
            float4 v = *(const float4*)(A + (size_t)(m0 + r) * lda + kc + k4);
            int mt = r >> 4, rl = r & 15, kb = k4 >> 3, e = k4 & 7;
            int addr = mt * 1024 + kb * 128 + ((rl ^ kb) << 3) + e;
            ushort4 hi, lo;
            hi.x = f2bf(v.x); hi.y = f2bf(v.y); hi.z = f2bf(v.z); hi.w = f2bf(v.w);
            *(ushort4*)&s_mem[addr] = hi;
            if (SPLIT) {
                lo.x = f2bf(v.x - bf2f(hi.x)); lo.y = f2bf(v.y - bf2f(hi.y));
                lo.z = f2bf(v.z - bf2f(hi.z)); lo.w = f2bf(v.w - bf2f(hi.w));
                *(ushort4*)&s_mem[AL + addr] = lo;
            }
        }
        // ---- stage B (linear copy from pre-tiled global)
        {
            const int ktile = kc >> 6;
            #pragma unroll
            for (int it = 0; it < 4; ++it) {
                int f = t + (it << 8);          // [0,1024) float4s
                int j = f >> 7, w8 = f & 127;   // tile j, f4-within
                size_t gt = ((size_t)(nb0 / 16 + j) * b_nkt + ktile) * 1024;
                *(float4*)&s_mem[BH + j * 1024 + w8 * 8] = ((const float4*)(Bh + gt))[w8];
                if (SPLIT)
                    *(float4*)&s_mem[BL + j * 1024 + w8 * 8] = ((const float4*)(Bl + gt))[w8];
            }
        }
        __syncthreads();
        // ---- compute
        #pragma unroll
        for (int s = 0; s < 2; ++s) {
            const int kb = (s << 2) + g;
            bf16x8 a_h[4], a_l[4], b_h[4], b_l[4];
            #pragma unroll
            for (int i = 0; i < 4; ++i) {
                int aaddr = (wm * 4 + i) * 1024 + kb * 128 + (((rr ^ kb) & 15) << 3);
                a_h[i] = *(const bf16x8*)&s_mem[aaddr];
                if (SPLIT) a_l[i] = *(const bf16x8*)&s_mem[AL + aaddr];
                int baddr = (wn * 4 + i) * 1024 + kb * 128 + (rr << 3);
                b_h[i] = *(const bf16x8*)&s_mem[BH + baddr];
                if (SPLIT) b_l[i] = *(const bf16x8*)&s_mem[BL + baddr];
            }
            #pragma unroll
            for (int mi = 0; mi < 4; ++mi)
                #pragma unroll
                for (int ni = 0; ni < 4; ++ni) {
                    acc[mi][ni] = __builtin_amdgcn_mfma_f32_16x16x32_bf16(a_h[mi], b_h[ni], acc[mi][ni], 0, 0, 0);
                    if (SPLIT) {
                        acc[mi][ni] = __builtin_amdgcn_mfma_f32_16x16x32_bf16(a_h[mi], b_l[ni], acc[mi][ni], 0, 0, 0);
                        acc[mi][ni] = __builtin_amdgcn_mfma_f32_16x16x32_bf16(a_l[mi], b_h[ni], acc[mi][ni], 0, 0, 0);
                    }
                }
        }
        __syncthreads();
    }
    // ---- epilogue via LDS bounce (coalesced fp32 stores)
    float* sf = (float*)s_mem;
    for (int rm = 0; rm < 2; ++rm) {
        if (wm == rm) {
            #pragma unroll
            for (int mi = 0; mi < 4; ++mi)
                #pragma unroll
                for (int ni = 0; ni < 4; ++ni)
                    #pragma unroll
                    for (int rg = 0; rg < 4; ++rg)
                        sf[(mi * 16 + g * 4 + rg) * 128 + wn * 64 + ni * 16 + rr] = acc[mi][ni][rg];
        }
        __syncthreads();
        #pragma unroll
        for (int it = 0; it < 8; ++it) {
            int f = t + (it << 8);
            int r = f >> 5, c4 = (f & 31) << 2;
            float4 v = *(const float4*)&sf[r * 128 + c4];
            int gr = m0 + rm * 64 + r, gc = nb0 + c4;
            float* op = out + (size_t)gr * outw + gc;
            if (init) {
                v.x += bias[biasoff + gc + 0]; v.y += bias[biasoff + gc + 1];
                v.z += bias[biasoff + gc + 2]; v.w += bias[biasoff + gc + 3];
            } else {
                float4 o = *(const float4*)op;
                v.x += o.x; v.y += o.y; v.z += o.z; v.w += o.w;
            }
            if (relu) {
                v.x = fmaxf(v.x, 0.f); v.y = fmaxf(v.y, 0.f);
                v.z = fmaxf(v.z, 0.f); v.w = fmaxf(v.w, 0.f);
            }
            *(float4*)op = v;
        }
        __syncthreads();
    }
}

// ---------- distance argmin (bf16 MFMA + margin + fp32 rescore) + gather ----------
// encq: enc fp32 in the quantized-output region; overwritten with cb[argmin] at the end.
__global__ __launch_bounds__(512) void k_dist(
    float* encq, const unsigned short* __restrict__ ch,
    const float* __restrict__ hsq, const float* __restrict__ cb)
{
    __shared__ __align__(16) unsigned short s_cb[16 * 1024];
    __shared__ __align__(16) float s_erow[EMB];
    __shared__ float s_rb[4][32], s_rs2[4][32];
    __shared__ int s_rbi[4][32];
    __shared__ int s_bi[32], s_need[32];
    __shared__ float s_wb[8]; __shared__ int s_wi[8];

    const int t = threadIdx.x;
    const int lane = t & 63, wv = t >> 6;
    const int g = lane >> 4, rr = lane & 15;
    const int mt = wv >> 2, cq = wv & 3;
    const int r0 = blockIdx.x * 32;

    // e fragments (bf16 hi) held in registers, full K=256
    bf16x8 eh[8];
    {
        const float* ep = encq + (size_t)(r0 + mt * 16 + rr) * EMB + g * 8;
        #pragma unroll
        for (int s = 0; s < 8; ++s) {
            float4 v0 = *(const float4*)(ep + s * 32);
            float4 v1 = *(const float4*)(ep + s * 32 + 4);
            bf16x8 a;
            a[0] = (short)f2bf(v0.x); a[1] = (short)f2bf(v0.y);
            a[2] = (short)f2bf(v0.z); a[3] = (short)f2bf(v0.w);
            a[4] = (short)f2bf(v1.x); a[5] = (short)f2bf(v1.y);
            a[6] = (short)f2bf(v1.z); a[7] = (short)f2bf(v1.w);
            eh[s] = a;
        }
    }
    float bst[4] = {-1e30f, -1e30f, -1e30f, -1e30f};
    float sec[4] = {-1e30f, -1e30f, -1e30f, -1e30f};
    int bidx[4] = {0, 0, 0, 0};

    for (int chunk = 0; chunk < NCODE / 64; ++chunk) {
        __syncthreads();
        #pragma unroll
        for (int it = 0; it < 4; ++it) {
            int f = t + (it << 9);          // [0,2048) f4s
            int j = f >> 7, w8 = f & 127;
            size_t gt = ((size_t)(chunk * 4 + (j >> 2)) * 4 + (j & 3)) * 1024;
            *(float4*)&s_cb[j * 1024 + w8 * 8] = ((const float4*)(ch + gt))[w8];
        }
        __syncthreads();
        f32x4 acc = (f32x4){0.f, 0.f, 0.f, 0.f};
        #pragma unroll
        for (int s = 0; s < 8; ++s) {
            bf16x8 b = *(const bf16x8*)&s_cb[(cq * 4 + (s >> 1)) * 1024 + ((s & 1) * 4 + g) * 128 + rr * 8];
            acc = __builtin_amdgcn_mfma_f32_16x16x32_bf16(eh[s], b, acc, 0, 0, 0);
        }
        const int code = (chunk << 6) + (cq << 4) + rr;
        const float hs = hsq[code];
        #pragma unroll
        for (int r2 = 0; r2 < 4; ++r2) {
            float v = acc[r2] - hs;
            if (v > bst[r2]) { sec[r2] = bst[r2]; bst[r2] = v; bidx[r2] = code; }
            else if (v > sec[r2]) sec[r2] = v;
        }
    }
    // intra-wave top-2 merge across the 16 code-lanes
    #pragma unroll
    for (int off = 1; off <= 8; off <<= 1) {
        #pragma unroll
        for (int r2 = 0; r2 < 4; ++r2) {
            float ob = __shfl_xor(bst[r2], off);
            float os2 = __shfl_xor(sec[r2], off);
            int oi = __shfl_xor(bidx[r2], off);
            if (ob > bst[r2] || (ob == bst[r2] && oi < bidx[r2])) {
                sec[r2] = fmaxf(bst[r2], fmaxf(sec[r2], os2));
                bst[r2] = ob; bidx[r2] = oi;
            } else {
                sec[r2] = fmaxf(sec[r2], fmaxf(ob, os2));
            }
        }
    }
    if (rr == 0) {
        #pragma unroll
        for (int r2 = 0; r2 < 4; ++r2) {
            int rl = mt * 16 + g * 4 + r2;
            s_rb[cq][rl] = bst[r2]; s_rs2[cq][rl] = sec[r2]; s_rbi[cq][rl] = bidx[r2];
        }
    }
    __syncthreads();
    if (t < 32) {
        float b = s_rb[0][t], s2 = s_rs2[0][t]; int bi = s_rbi[0][t];
        #pragma unroll
        for (int w = 1; w < 4; ++w) {
            float ob = s_rb[w][t], os2 = s_rs2[w][t]; int oi = s_rbi[w][t];
            if (ob > b || (ob == b && oi < bi)) { s2 = fmaxf(b, fmaxf(s2, os2)); b = ob; bi = oi; }
            else s2 = fmaxf(s2, fmaxf(ob, os2));
        }
        s_bi[t] = bi;
        s_need[t] = (b - s2 <= 0.5f) ? 1 : 0;
    }
    __syncthreads();
    // exact fp32 rescore for margin-flagged rows (uniform branching: s_need is shared)
    for (int r = 0; r < 32; ++r) {
        if (!s_need[r]) continue;
        if (t < 64) ((float4*)s_erow)[t] = ((const float4*)(encq + (size_t)(r0 + r) * EMB))[t];
        __syncthreads();
        float lb = -1e30f; int li = NCODE;
        for (int c = t; c < NCODE; c += 512) {
            const float4* cp = (const float4*)(cb + (size_t)c * EMB);
            float dot = 0.f;
            #pragma unroll 16
            for (int k = 0; k < 64; ++k) {
                float4 ev = ((const float4*)s_erow)[k];
                float4 cv = cp[k];
                dot += ev.x * cv.x + ev.y * cv.y + ev.z * cv.z + ev.w * cv.w;
            }
            float sc = dot - hsq[c];
            if (sc > lb || (sc == lb && c < li)) { lb = sc; li = c; }
        }
        #pragma unroll
        for (int off = 32; off >= 1; off >>= 1) {
            float ov = __shfl_down(lb, off); int oi = __shfl_down(li, off);
            if (ov > lb || (ov == lb && oi < li)) { lb = ov; li = oi; }
        }
        if (lane == 0) { s_wb[wv] = lb; s_wi[wv] = li; }
        __syncthreads();
        if (t == 0) {
            float b = s_wb[0]; int bi = s_wi[0];
            for (int w = 1; w < 8; ++w)
                if (s_wb[w] > b || (s_wb[w] == b && s_wi[w] < bi)) { b = s_wb[w]; bi = s_wi[w]; }
            s_bi[r] = bi;
        }
        __syncthreads();
    }
    __syncthreads();
    // gather: overwrite enc rows with cb[argmin] (all enc reads for this block are done)
    #pragma unroll
    for (int it = 0; it < 4; ++it) {
        int f = t + (it << 9);
        int row = f >> 6, c4 = (f & 63) << 2;
        int bi = s_bi[row];
        *(float4*)(encq + (size_t)(r0 + row) * EMB + c4) =
            *(const float4*)(cb + (size_t)bi * EMB + c4);
    }
}

// ---------- fallback fp32 decoder (round-1, reads q from outq) ----------
__global__ __launch_bounds__(256) void k_dec_fb(
    const float* __restrict__ qz,
    const float* __restrict__ W3, const float* __restrict__ b3,
    const float* __restrict__ W4, const float* __restrict__ b4,
    float* __restrict__ outd) {
    __shared__ float s_q[8][EMB];
    __shared__ float s_h2[8][HID];
    const int t = threadIdx.x;
    const int row0 = blockIdx.x * 8;
    #pragma unroll
    for (int r = 0; r < 8; ++r) s_q[r][t] = qz[(size_t)(row0 + r) * EMB + t];
    __syncthreads();
    for (int gg = 0; gg < 8; ++gg) {
        const int j = (gg << 8) + t;
        float acc[8];
        #pragma unroll
        for (int r = 0; r < 8; ++r) acc[r] = 0.f;
        const float* wp = W3 + j;
        for (int e = 0; e < EMB; e += 4) {
            const float w0 = wp[(size_t)(e + 0) * HID];
            const float w1v = wp[(size_t)(e + 1) * HID];
            const float w2v = wp[(size_t)(e + 2) * HID];
            const float w3v = wp[(size_t)(e + 3) * HID];
            #pragma unroll
            for (int r = 0; r < 8; ++r) {
                const float4 qv = *reinterpret_cast<const float4*>(&s_q[r][e]);
                acc[r] = fmaf(qv.x, w0, acc[r]);
                acc[r] = fmaf(qv.y, w1v, acc[r]);
                acc[r] = fmaf(qv.z, w2v, acc[r]);
                acc[r] = fmaf(qv.w, w3v, acc[r]);
            }
        }
        const float bb = b3[j];
        #pragma unroll
        for (int r = 0; r < 8; ++r) s_h2[r][j] = fmaxf(acc[r] + bb, 0.f);
    }
    __syncthreads();
    float acc4[8][4];
    #pragma unroll
    for (int r = 0; r < 8; ++r)
        #pragma unroll
        for (int ci = 0; ci < 4; ++ci) acc4[r][ci] = 0.f;
    const float* w4p = W4 + t;
    for (int k = 0; k < HID; k += 4) {
        float wv[4][4];
        #pragma unroll
        for (int ki = 0; ki < 4; ++ki)
            #pragma unroll
            for (int ci = 0; ci < 4; ++ci)
                wv[ki][ci] = w4p[(size_t)(k + ki) * IN_DIM + (ci << 8)];
        #pragma unroll
        for (int r = 0; r < 8; ++r) {
            const float4 hv = *reinterpret_cast<const float4*>(&s_h2[r][k]);
            #pragma unroll
            for (int ci = 0; ci < 4; ++ci) {
                acc4[r][ci] = fmaf(hv.x, wv[0][ci], acc4[r][ci]);
                acc4[r][ci] = fmaf(hv.y, wv[1][ci], acc4[r][ci]);
                acc4[r][ci] = fmaf(hv.z, wv[2][ci], acc4[r][ci]);
                acc4[r][ci] = fmaf(hv.w, wv[3][ci], acc4[r][ci]);
            }
        }
    }
    #pragma unroll
    for (int ci = 0; ci < 4; ++ci) {
        const float bb = b4[(ci << 8) + t];
        #pragma unroll
        for (int r = 0; r < 8; ++r)
            outd[(size_t)(row0 + r) * IN_DIM + (ci << 8) + t] = acc4[r][ci] + bb;
    }
}

extern "C" void kernel_launch(void* const* d_in, const int* in_sizes, int n_in,
                              void* d_out, int out_size, void* d_ws, size_t ws_size,
                              hipStream_t stream) {
    const float* x  = (const float*)d_in[0];
    const float* W1 = (const float*)d_in[1];
    const float* b1 = (const float*)d_in[2];
    const float* W2 = (const float*)d_in[3];
    const float* b2 = (const float*)d_in[4];
    const float* cb = (const float*)d_in[5];
    const float* W3 = (const float*)d_in[6];
    const float* b3 = (const float*)d_in[7];
    const float* W4 = (const float*)d_in[8];
    const float* b4 = (const float*)d_in[9];

    float* outq = (float*)d_out;                       // [N,256]
    float* outd = outq + (size_t)N_ROWS * EMB;         // [N,1024]

    // scratch in the decoded-output region (dead before decoder writes it)
    unsigned short* ou = (unsigned short*)outd;
    unsigned short* W1Th = ou;                         // 2M ushort
    unsigned short* W1Tl = ou + 2097152;               // 2M
    unsigned short* W2Th = ou + 4194304;               // 512K
    unsigned short* W2Tl = ou + 4718592;               // 512K
    unsigned short* cbh  = ou + 5242880;               // 1M
    float* halfsq = outd + 3145728;                    // 4K floats
    float* hbuf   = outd + 4194304;                    // N*512 fp32 (128 MiB)
    float* enc    = outq;                              // N*256 fp32, consumed by k_dist

    const bool fastdec = ws_size >= (size_t)139460608; // W3T(1M)+W4T(4M)+h2(128M)
    unsigned short* W3Th = (unsigned short*)d_ws;
    unsigned short* W4Th = W3Th + 524288;
    float* h2buf = (float*)((char*)d_ws + 5242880);

    // prep: weight/codebook conversion
    k_conv_w<1><<<dim3(128, 16), 256, 0, stream>>>(W1, W1Th, W1Tl, HID, 16);
    k_conv_w<1><<<dim3(16, 32), 256, 0, stream>>>(W2, W2Th, W2Tl, EMB, 32);
    k_conv_cb<<<256, 256, 0, stream>>>(cb, cbh, halfsq);
    if (fastdec) {
        k_conv_w<0><<<dim3(128, 4), 256, 0, stream>>>(W3, W3Th, nullptr, HID, 4);
        k_conv_w<0><<<dim3(64, 32), 256, 0, stream>>>(W4, W4Th, nullptr, IN_DIM, 32);
    }
    // encoder: split-bf16, hidden in quarters (h fp32 staged in outd)
    for (int q = 0; q < 4; ++q) {
        k_layer<1><<<dim3(512, 4), 256, 0, stream>>>(
            x, IN_DIM, IN_DIM, W1Th + (size_t)q * 524288, W1Tl + (size_t)q * 524288, 16,
            b1, q * 512, hbuf, 512, 1, 1);
        k_layer<1><<<dim3(512, 2), 256, 0, stream>>>(
            hbuf, 512, 512, W2Th + (size_t)q * 8192, W2Tl + (size_t)q * 8192, 32,
            b2, 0, enc, EMB, 0, q == 0);
    }
    // nearest-code + gather (writes quantized output in place)
    k_dist<<<2048, 512, 0, stream>>>(enc, cbh, halfsq, cb);
    // decoder
    if (fastdec) {
        for (int q = 0; q < 4; ++q) {
            k_layer<0><<<dim3(512, 4), 256, 0, stream>>>(
                outq, EMB, EMB, W3Th + (size_t)q * 131072, nullptr, 4,
                b3, q * 512, h2buf, 512, 1, 1);
            k_layer<0><<<dim3(512, 8), 256, 0, stream>>>(
                h2buf, 512, 512, W4Th + (size_t)q * 8192, nullptr, 32,
                b4, 0, outd, IN_DIM, 0, q == 0);
        }
    } else {
        k_dec_fb<<<N_ROWS / 8, 256, 0, stream>>>(outq, W3, b3, W4, b4, outd);
    }
}

// Round 4
// 4204.361 us; speedup vs baseline: 3.9267x; 1.8852x over previous
//
#include <hip/hip_runtime.h>

#define N_ROWS 65536
#define IN_DIM 1024
#define HID    2048
#define EMB    256
#define NCODE  4096

typedef __attribute__((ext_vector_type(8))) short bf16x8;
typedef __attribute__((ext_vector_type(4))) float f32x4;

__device__ __forceinline__ unsigned short f2bf(float v) {
    unsigned u = __float_as_uint(v);
    u += 0x7FFFu + ((u >> 16) & 1u);
    return (unsigned short)(u >> 16);
}
__device__ __forceinline__ float bf2f(unsigned short h) {
    return __uint_as_float(((unsigned)h) << 16);
}

// ---------- weight pre-convert (+transpose) into tiled fragment layout ----------
// src: [K][NC] fp32 row-major. dst: tiles (nt,kt) of 16 cols x 64 k, elem (rr,k):
//   tile*1024 + ((k>>3)&7)*128 + rr*8 + (k&7)
template<int SPLIT>
__global__ __launch_bounds__(256) void k_conv_w(
    const float* __restrict__ src, unsigned short* __restrict__ dh,
    unsigned short* __restrict__ dl, int NC, int nkt)
{
    const int t = threadIdx.x;
    const int nt = blockIdx.x, kt = blockIdx.y;
    const int kk = t >> 2, j4 = (t & 3) << 2;
    const int k0 = kt << 6, n0 = nt << 4;
    float4 v = *(const float4*)(src + (size_t)(k0 + kk) * NC + n0 + j4);
    size_t tb = ((size_t)nt * nkt + kt) * 1024 + ((kk >> 3) * 128) + (kk & 7);
    float vv[4] = {v.x, v.y, v.z, v.w};
    #pragma unroll
    for (int j = 0; j < 4; ++j) {
        unsigned short h = f2bf(vv[j]);
        dh[tb + (size_t)(j4 + j) * 8] = h;
        if (SPLIT) dl[tb + (size_t)(j4 + j) * 8] = f2bf(vv[j] - bf2f(h));
    }
}

// ---------- codebook convert (tiled bf16 hi+lo, no transpose) + 0.5*||c||^2 ----------
__global__ __launch_bounds__(256) void k_conv_cb(
    const float* __restrict__ cb, unsigned short* __restrict__ ch,
    unsigned short* __restrict__ cl_, float* __restrict__ halfsq)
{
    const int t = threadIdx.x;
    const int ct = blockIdx.x;
    const int cl = t >> 4, f = t & 15;
    const int code = (ct << 4) + cl;
    float ssq = 0.f;
    #pragma unroll
    for (int it = 0; it < 4; ++it) {
        const int k4 = (f << 2) + (it << 6);
        float4 v = *(const float4*)(cb + (size_t)code * EMB + k4);
        ssq += v.x * v.x + v.y * v.y + v.z * v.z + v.w * v.w;
        size_t tb = ((size_t)(ct * 4 + (k4 >> 6))) * 1024 + ((k4 >> 3) & 7) * 128 + cl * 8 + (k4 & 7);
        ushort4 h = { f2bf(v.x), f2bf(v.y), f2bf(v.z), f2bf(v.w) };
        *(ushort4*)&ch[tb] = h;
        ushort4 lo = { f2bf(v.x - bf2f(h.x)), f2bf(v.y - bf2f(h.y)),
                       f2bf(v.z - bf2f(h.z)), f2bf(v.w - bf2f(h.w)) };
        *(ushort4*)&cl_[tb] = lo;
    }
    #pragma unroll
    for (int off = 1; off <= 8; off <<= 1) ssq += __shfl_xor(ssq, off);
    if (f == 0) halfsq[code] = 0.5f * ssq;
}

// ---------- generic MFMA layer: out = [relu](A @ B + bias)  (split-bf16 optional) ----------
template<int SPLIT>
__global__ __launch_bounds__(256) void k_layer(
    const float* __restrict__ A, int lda, int K,
    const unsigned short* __restrict__ Bh, const unsigned short* __restrict__ Bl,
    int b_nkt, const float* __restrict__ bias, int biasoff,
    float* __restrict__ out, int outw, int relu, int init)
{
    constexpr int AL = 8192;
    constexpr int BH = SPLIT ? 16384 : 8192;
    constexpr int BL = SPLIT ? 24576 : 8192;
    __shared__ __align__(16) unsigned short s_mem[SPLIT ? 32768 : 16384];

    const int t = threadIdx.x;
    const int m0 = blockIdx.x * 128;
    const int nb0 = blockIdx.y * 128;
    const int lane = t & 63, wv = t >> 6;
    const int wm = wv >> 1, wn = wv & 1;
    const int g = lane >> 4, rr = lane & 15;

    f32x4 acc[4][4];
    #pragma unroll
    for (int mi = 0; mi < 4; ++mi)
        #pragma unroll
        for (int ni = 0; ni < 4; ++ni) acc[mi][ni] = (f32x4){0.f, 0.f, 0.f, 0.f};

    for (int kc = 0; kc < K; kc += 64) {
        #pragma unroll
        for (int it = 0; it < 8; ++it) {
            int f = t + (it << 8);
            int r = f >> 4, k4 = (f & 15) << 2;
            float4 v = *(const float4*)(A + (size_t)(m0 + r) * lda + kc + k4);
            int mt = r >> 4, rl = r & 15, kb = k4 >> 3, e = k4 & 7;
            int addr = mt * 1024 + kb * 128 + ((rl ^ kb) << 3) + e;
            ushort4 hi, lo;
            hi.x = f2bf(v.x); hi.y = f2bf(v.y); hi.z = f2bf(v.z); hi.w = f2bf(v.w);
            *(ushort4*)&s_mem[addr] = hi;
            if (SPLIT) {
                lo.x = f2bf(v.x - bf2f(hi.x)); lo.y = f2bf(v.y - bf2f(hi.y));
                lo.z = f2bf(v.z - bf2f(hi.z)); lo.w = f2bf(v.w - bf2f(hi.w));
                *(ushort4*)&s_mem[AL + addr] = lo;
            }
        }
        {
            const int ktile = kc >> 6;
            #pragma unroll
            for (int it = 0; it < 4; ++it) {
                int f = t + (it << 8);
                int j = f >> 7, w8 = f & 127;
                size_t gt = ((size_t)(nb0 / 16 + j) * b_nkt + ktile) * 1024;
                *(float4*)&s_mem[BH + j * 1024 + w8 * 8] = ((const float4*)(Bh + gt))[w8];
                if (SPLIT)
                    *(float4*)&s_mem[BL + j * 1024 + w8 * 8] = ((const float4*)(Bl + gt))[w8];
            }
        }
        __syncthreads();
        #pragma unroll
        for (int s = 0; s < 2; ++s) {
            const int kb = (s << 2) + g;
            bf16x8 a_h[4], a_l[4], b_h[4], b_l[4];
            #pragma unroll
            for (int i = 0; i < 4; ++i) {
                int aaddr = (wm * 4 + i) * 1024 + kb * 128 + (((rr ^ kb) & 15) << 3);
                a_h[i] = *(const bf16x8*)&s_mem[aaddr];
                if (SPLIT) a_l[i] = *(const bf16x8*)&s_mem[AL + aaddr];
                int baddr = (wn * 4 + i) * 1024 + kb * 128 + (rr << 3);
                b_h[i] = *(const bf16x8*)&s_mem[BH + baddr];
                if (SPLIT) b_l[i] = *(const bf16x8*)&s_mem[BL + baddr];
            }
            #pragma unroll
            for (int mi = 0; mi < 4; ++mi)
                #pragma unroll
                for (int ni = 0; ni < 4; ++ni) {
                    acc[mi][ni] = __builtin_amdgcn_mfma_f32_16x16x32_bf16(a_h[mi], b_h[ni], acc[mi][ni], 0, 0, 0);
                    if (SPLIT) {
                        acc[mi][ni] = __builtin_amdgcn_mfma_f32_16x16x32_bf16(a_h[mi], b_l[ni], acc[mi][ni], 0, 0, 0);
                        acc[mi][ni] = __builtin_amdgcn_mfma_f32_16x16x32_bf16(a_l[mi], b_h[ni], acc[mi][ni], 0, 0, 0);
                    }
                }
        }
        __syncthreads();
    }
    float* sf = (float*)s_mem;
    for (int rm = 0; rm < 2; ++rm) {
        if (wm == rm) {
            #pragma unroll
            for (int mi = 0; mi < 4; ++mi)
                #pragma unroll
                for (int ni = 0; ni < 4; ++ni)
                    #pragma unroll
                    for (int rg = 0; rg < 4; ++rg)
                        sf[(mi * 16 + g * 4 + rg) * 128 + wn * 64 + ni * 16 + rr] = acc[mi][ni][rg];
        }
        __syncthreads();
        #pragma unroll
        for (int it = 0; it < 8; ++it) {
            int f = t + (it << 8);
            int r = f >> 5, c4 = (f & 31) << 2;
            float4 v = *(const float4*)&sf[r * 128 + c4];
            int gr = m0 + rm * 64 + r, gc = nb0 + c4;
            float* op = out + (size_t)gr * outw + gc;
            if (init) {
                v.x += bias[biasoff + gc + 0]; v.y += bias[biasoff + gc + 1];
                v.z += bias[biasoff + gc + 2]; v.w += bias[biasoff + gc + 3];
            } else {
                float4 o = *(const float4*)op;
                v.x += o.x; v.y += o.y; v.z += o.z; v.w += o.w;
            }
            if (relu) {
                v.x = fmaxf(v.x, 0.f); v.y = fmaxf(v.y, 0.f);
                v.z = fmaxf(v.z, 0.f); v.w = fmaxf(v.w, 0.f);
            }
            *(float4*)op = v;
        }
        __syncthreads();
    }
}

// ---------- distance argmin (split-bf16 MFMA + tight margin + fp32 rescore) + gather ----------
// 64 rows/block, 512 threads. Scores fp32-grade (err <~5e-4), margin 0.02 flags ~0.7% rows.
__global__ __launch_bounds__(512) void k_dist(
    float* encq, const unsigned short* __restrict__ ch,
    const unsigned short* __restrict__ cl,
    const float* __restrict__ hsq, const float* __restrict__ cb)
{
    __shared__ __align__(16) unsigned short s_cb[32768];   // 64 KB: hi [0:16384), lo [16384:32768)
    __shared__ __align__(16) float s_erow[EMB];
    __shared__ float s_rb[2][64], s_rs2[2][64];
    __shared__ int s_rbi[2][64];
    __shared__ int s_bi[64], s_need[64];
    __shared__ float s_wb[8]; __shared__ int s_wi[8];

    const int t = threadIdx.x;
    const int lane = t & 63, wv = t >> 6;
    const int g = lane >> 4, rr = lane & 15;
    const int mt = wv >> 1, cq = wv & 1;       // 4 row-groups x 2 code-halves
    const int r0 = blockIdx.x * 64;

    // e fragments hi+lo in registers, full K=256
    bf16x8 eh[8], el[8];
    {
        const float* ep = encq + (size_t)(r0 + mt * 16 + rr) * EMB + g * 8;
        #pragma unroll
        for (int s = 0; s < 8; ++s) {
            float4 v0 = *(const float4*)(ep + s * 32);
            float4 v1 = *(const float4*)(ep + s * 32 + 4);
            float vv[8] = {v0.x, v0.y, v0.z, v0.w, v1.x, v1.y, v1.z, v1.w};
            bf16x8 a, b;
            #pragma unroll
            for (int j = 0; j < 8; ++j) {
                unsigned short h = f2bf(vv[j]);
                a[j] = (short)h;
                b[j] = (short)f2bf(vv[j] - bf2f(h));
            }
            eh[s] = a; el[s] = b;
        }
    }
    float bst[4] = {-1e30f, -1e30f, -1e30f, -1e30f};
    float sec[4] = {-1e30f, -1e30f, -1e30f, -1e30f};
    int bidx[4] = {0, 0, 0, 0};

    for (int chunk = 0; chunk < NCODE / 64; ++chunk) {
        __syncthreads();
        {   // stage 64 codes hi+lo: 2048 float4 each (LDS layout == global tiled layout)
            const float4* gh = (const float4*)(ch + (size_t)chunk * 16384);
            const float4* gl = (const float4*)(cl + (size_t)chunk * 16384);
            #pragma unroll
            for (int it = 0; it < 4; ++it) {
                int f = t + (it << 9);          // [0,2048)
                *(float4*)&s_cb[f * 8] = gh[f];
                *(float4*)&s_cb[16384 + f * 8] = gl[f];
            }
        }
        __syncthreads();
        f32x4 acc[2];
        acc[0] = (f32x4){0.f, 0.f, 0.f, 0.f};
        acc[1] = (f32x4){0.f, 0.f, 0.f, 0.f};
        #pragma unroll
        for (int s = 0; s < 8; ++s) {
            const int ktile = s >> 1, kb = ((s & 1) << 2) + g;
            #pragma unroll
            for (int ci = 0; ci < 2; ++ci) {
                const int off = ((cq * 2 + ci) * 4 + ktile) * 1024 + kb * 128 + rr * 8;
                bf16x8 bh = *(const bf16x8*)&s_cb[off];
                bf16x8 bl = *(const bf16x8*)&s_cb[16384 + off];
                acc[ci] = __builtin_amdgcn_mfma_f32_16x16x32_bf16(eh[s], bh, acc[ci], 0, 0, 0);
                acc[ci] = __builtin_amdgcn_mfma_f32_16x16x32_bf16(eh[s], bl, acc[ci], 0, 0, 0);
                acc[ci] = __builtin_amdgcn_mfma_f32_16x16x32_bf16(el[s], bh, acc[ci], 0, 0, 0);
            }
        }
        #pragma unroll
        for (int ci = 0; ci < 2; ++ci) {
            const int code = (chunk << 6) + (cq << 5) + (ci << 4) + rr;
            const float hs = hsq[code];
            #pragma unroll
            for (int r2 = 0; r2 < 4; ++r2) {
                float v = acc[ci][r2] - hs;
                if (v > bst[r2]) { sec[r2] = bst[r2]; bst[r2] = v; bidx[r2] = code; }
                else if (v > sec[r2]) sec[r2] = v;
            }
        }
    }
    // merge across the 16 code-lanes (lane bits 0..3)
    #pragma unroll
    for (int off = 1; off <= 8; off <<= 1) {
        #pragma unroll
        for (int r2 = 0; r2 < 4; ++r2) {
            float ob = __shfl_xor(bst[r2], off);
            float os2 = __shfl_xor(sec[r2], off);
            int oi = __shfl_xor(bidx[r2], off);
            if (ob > bst[r2] || (ob == bst[r2] && oi < bidx[r2])) {
                sec[r2] = fmaxf(bst[r2], fmaxf(sec[r2], os2));
                bst[r2] = ob; bidx[r2] = oi;
            } else {
                sec[r2] = fmaxf(sec[r2], fmaxf(ob, os2));
            }
        }
    }
    if (rr == 0) {
        #pragma unroll
        for (int r2 = 0; r2 < 4; ++r2) {
            int rl = mt * 16 + g * 4 + r2;
            s_rb[cq][rl] = bst[r2]; s_rs2[cq][rl] = sec[r2]; s_rbi[cq][rl] = bidx[r2];
        }
    }
    __syncthreads();
    if (t < 64) {
        float b = s_rb[0][t], s2 = s_rs2[0][t]; int bi = s_rbi[0][t];
        float ob = s_rb[1][t], os2 = s_rs2[1][t]; int oi = s_rbi[1][t];
        if (ob > b || (ob == b && oi < bi)) { s2 = fmaxf(b, fmaxf(s2, os2)); b = ob; bi = oi; }
        else s2 = fmaxf(s2, fmaxf(ob, os2));
        s_bi[t] = bi;
        s_need[t] = (b - s2 <= 0.02f) ? 1 : 0;
    }
    __syncthreads();
    // exact fp32 rescore for margin-flagged rows (uniform branch: s_need is shared)
    for (int r = 0; r < 64; ++r) {
        if (!s_need[r]) continue;
        if (t < 64) ((float4*)s_erow)[t] = ((const float4*)(encq + (size_t)(r0 + r) * EMB))[t];
        __syncthreads();
        float lb = -1e30f; int li = NCODE;
        for (int c = t; c < NCODE; c += 512) {
            const float4* cp = (const float4*)(cb + (size_t)c * EMB);
            float dot = 0.f;
            #pragma unroll 16
            for (int k = 0; k < 64; ++k) {
                float4 ev = ((const float4*)s_erow)[k];
                float4 cv = cp[k];
                dot += ev.x * cv.x + ev.y * cv.y + ev.z * cv.z + ev.w * cv.w;
            }
            float sc = dot - hsq[c];
            if (sc > lb || (sc == lb && c < li)) { lb = sc; li = c; }
        }
        #pragma unroll
        for (int off = 32; off >= 1; off >>= 1) {
            float ov = __shfl_down(lb, off); int oi = __shfl_down(li, off);
            if (ov > lb || (ov == lb && oi < li)) { lb = ov; li = oi; }
        }
        if (lane == 0) { s_wb[wv] = lb; s_wi[wv] = li; }
        __syncthreads();
        if (t == 0) {
            float b = s_wb[0]; int bi = s_wi[0];
            for (int w = 1; w < 8; ++w)
                if (s_wb[w] > b || (s_wb[w] == b && s_wi[w] < bi)) { b = s_wb[w]; bi = s_wi[w]; }
            s_bi[r] = bi;
        }
        __syncthreads();
    }
    __syncthreads();
    // gather: overwrite enc rows with cb[argmin]
    #pragma unroll
    for (int it = 0; it < 8; ++it) {
        int f = t + (it << 9);
        int row = f >> 6, c4 = (f & 63) << 2;
        int bi = s_bi[row];
        *(float4*)(encq + (size_t)(r0 + row) * EMB + c4) =
            *(const float4*)(cb + (size_t)bi * EMB + c4);
    }
}

// ---------- fallback fp32 decoder ----------
__global__ __launch_bounds__(256) void k_dec_fb(
    const float* __restrict__ qz,
    const float* __restrict__ W3, const float* __restrict__ b3,
    const float* __restrict__ W4, const float* __restrict__ b4,
    float* __restrict__ outd) {
    __shared__ float s_q[8][EMB];
    __shared__ float s_h2[8][HID];
    const int t = threadIdx.x;
    const int row0 = blockIdx.x * 8;
    #pragma unroll
    for (int r = 0; r < 8; ++r) s_q[r][t] = qz[(size_t)(row0 + r) * EMB + t];
    __syncthreads();
    for (int gg = 0; gg < 8; ++gg) {
        const int j = (gg << 8) + t;
        float acc[8];
        #pragma unroll
        for (int r = 0; r < 8; ++r) acc[r] = 0.f;
        const float* wp = W3 + j;
        for (int e = 0; e < EMB; e += 4) {
            const float w0 = wp[(size_t)(e + 0) * HID];
            const float w1v = wp[(size_t)(e + 1) * HID];
            const float w2v = wp[(size_t)(e + 2) * HID];
            const float w3v = wp[(size_t)(e + 3) * HID];
            #pragma unroll
            for (int r = 0; r < 8; ++r) {
                const float4 qv = *reinterpret_cast<const float4*>(&s_q[r][e]);
                acc[r] = fmaf(qv.x, w0, acc[r]);
                acc[r] = fmaf(qv.y, w1v, acc[r]);
                acc[r] = fmaf(qv.z, w2v, acc[r]);
                acc[r] = fmaf(qv.w, w3v, acc[r]);
            }
        }
        const float bb = b3[j];
        #pragma unroll
        for (int r = 0; r < 8; ++r) s_h2[r][j] = fmaxf(acc[r] + bb, 0.f);
    }
    __syncthreads();
    float acc4[8][4];
    #pragma unroll
    for (int r = 0; r < 8; ++r)
        #pragma unroll
        for (int ci = 0; ci < 4; ++ci) acc4[r][ci] = 0.f;
    const float* w4p = W4 + t;
    for (int k = 0; k < HID; k += 4) {
        float wv[4][4];
        #pragma unroll
        for (int ki = 0; ki < 4; ++ki)
            #pragma unroll
            for (int ci = 0; ci < 4; ++ci)
                wv[ki][ci] = w4p[(size_t)(k + ki) * IN_DIM + (ci << 8)];
        #pragma unroll
        for (int r = 0; r < 8; ++r) {
            const float4 hv = *reinterpret_cast<const float4*>(&s_h2[r][k]);
            #pragma unroll
            for (int ci = 0; ci < 4; ++ci) {
                acc4[r][ci] = fmaf(hv.x, wv[0][ci], acc4[r][ci]);
                acc4[r][ci] = fmaf(hv.y, wv[1][ci], acc4[r][ci]);
                acc4[r][ci] = fmaf(hv.z, wv[2][ci], acc4[r][ci]);
                acc4[r][ci] = fmaf(hv.w, wv[3][ci], acc4[r][ci]);
            }
        }
    }
    #pragma unroll
    for (int ci = 0; ci < 4; ++ci) {
        const float bb = b4[(ci << 8) + t];
        #pragma unroll
        for (int r = 0; r < 8; ++r)
            outd[(size_t)(row0 + r) * IN_DIM + (ci << 8) + t] = acc4[r][ci] + bb;
    }
}

extern "C" void kernel_launch(void* const* d_in, const int* in_sizes, int n_in,
                              void* d_out, int out_size, void* d_ws, size_t ws_size,
                              hipStream_t stream) {
    const float* x  = (const float*)d_in[0];
    const float* W1 = (const float*)d_in[1];
    const float* b1 = (const float*)d_in[2];
    const float* W2 = (const float*)d_in[3];
    const float* b2 = (const float*)d_in[4];
    const float* cb = (const float*)d_in[5];
    const float* W3 = (const float*)d_in[6];
    const float* b3 = (const float*)d_in[7];
    const float* W4 = (const float*)d_in[8];
    const float* b4 = (const float*)d_in[9];

    float* outq = (float*)d_out;                       // [N,256]
    float* outd = outq + (size_t)N_ROWS * EMB;         // [N,1024]

    // scratch in the decoded-output region (dead before decoder writes it)
    unsigned short* ou = (unsigned short*)outd;
    unsigned short* W1Th = ou;                         // 2M ushort
    unsigned short* W1Tl = ou + 2097152;               // 2M
    unsigned short* W2Th = ou + 4194304;               // 512K
    unsigned short* W2Tl = ou + 4718592;               // 512K
    unsigned short* cbh  = ou + 5242880;               // 1M
    unsigned short* cbl  = ou + 6291456;               // 1M
    float* halfsq = outd + 3670016;                    // 4K floats (after cbl)
    float* hbuf   = outd + 4194304;                    // N*512 fp32 (128 MiB)
    float* enc    = outq;                              // N*256 fp32, consumed by k_dist

    const bool fastdec = ws_size >= (size_t)139460608; // W3T(1M)+W4T(4M)+h2(128M)
    unsigned short* W3Th = (unsigned short*)d_ws;
    unsigned short* W4Th = W3Th + 524288;
    float* h2buf = (float*)((char*)d_ws + 5242880);

    // prep: weight/codebook conversion
    k_conv_w<1><<<dim3(128, 16), 256, 0, stream>>>(W1, W1Th, W1Tl, HID, 16);
    k_conv_w<1><<<dim3(16, 32), 256, 0, stream>>>(W2, W2Th, W2Tl, EMB, 32);
    k_conv_cb<<<256, 256, 0, stream>>>(cb, cbh, cbl, halfsq);
    if (fastdec) {
        k_conv_w<0><<<dim3(128, 4), 256, 0, stream>>>(W3, W3Th, nullptr, HID, 4);
        k_conv_w<0><<<dim3(64, 32), 256, 0, stream>>>(W4, W4Th, nullptr, IN_DIM, 32);
    }
    // encoder: split-bf16, hidden in quarters (h fp32 staged in outd)
    for (int q = 0; q < 4; ++q) {
        k_layer<1><<<dim3(512, 4), 256, 0, stream>>>(
            x, IN_DIM, IN_DIM, W1Th + (size_t)q * 524288, W1Tl + (size_t)q * 524288, 16,
            b1, q * 512, hbuf, 512, 1, 1);
        k_layer<1><<<dim3(512, 2), 256, 0, stream>>>(
            hbuf, 512, 512, W2Th + (size_t)q * 8192, W2Tl + (size_t)q * 8192, 32,
            b2, 0, enc, EMB, 0, q == 0);
    }
    // nearest-code + gather (writes quantized output in place)
    k_dist<<<1024, 512, 0, stream>>>(enc, cbh, cbl, halfsq, cb);
    // decoder
    if (fastdec) {
        for (int q = 0; q < 4; ++q) {
            k_layer<0><<<dim3(512, 4), 256, 0, stream>>>(
                outq, EMB, EMB, W3Th + (size_t)q * 131072, nullptr, 4,
                b3, q * 512, h2buf, 512, 1, 1);
            k_layer<0><<<dim3(512, 8), 256, 0, stream>>>(
                h2buf, 512, 512, W4Th + (size_t)q * 8192, nullptr, 32,
                b4, 0, outd, IN_DIM, 0, q == 0);
        }
    } else {
        k_dec_fb<<<N_ROWS / 8, 256, 0, stream>>>(outq, W3, b3, W4, b4, outd);
    }
}

// Round 5
// 3899.574 us; speedup vs baseline: 4.2336x; 1.0782x over previous
//
#include <hip/hip_runtime.h>

#define N_ROWS 65536
#define IN_DIM 1024
#define HID    2048
#define EMB    256
#define NCODE  4096

typedef __attribute__((ext_vector_type(8))) short bf16x8;
typedef __attribute__((ext_vector_type(4))) float f32x4;

__device__ __forceinline__ unsigned short f2bf(float v) {
    unsigned u = __float_as_uint(v);
    u += 0x7FFFu + ((u >> 16) & 1u);
    return (unsigned short)(u >> 16);
}
__device__ __forceinline__ float bf2f(unsigned short h) {
    return __uint_as_float(((unsigned)h) << 16);
}
// async global->LDS 16B: per-lane global src, wave-uniform LDS base (+lane*16 by HW)
__device__ __forceinline__ void gload16(const unsigned short* g, unsigned short* l) {
    __builtin_amdgcn_global_load_lds(
        (const __attribute__((address_space(1))) unsigned int*)g,
        (__attribute__((address_space(3))) unsigned int*)l, 16, 0, 0);
}

// ---------- weight pre-convert (+transpose) into tiled fragment layout ----------
// src: [K][NC] fp32 row-major. dst: tiles (nt,kt) of 16 cols x 64 k, elem (rr,k):
//   tile*1024 + ((k>>3)&7)*128 + rr*8 + (k&7)
template<int SPLIT>
__global__ __launch_bounds__(256) void k_conv_w(
    const float* __restrict__ src, unsigned short* __restrict__ dh,
    unsigned short* __restrict__ dl, int NC, int nkt)
{
    const int t = threadIdx.x;
    const int nt = blockIdx.x, kt = blockIdx.y;
    const int kk = t >> 2, j4 = (t & 3) << 2;
    const int k0 = kt << 6, n0 = nt << 4;
    float4 v = *(const float4*)(src + (size_t)(k0 + kk) * NC + n0 + j4);
    size_t tb = ((size_t)nt * nkt + kt) * 1024 + ((kk >> 3) * 128) + (kk & 7);
    float vv[4] = {v.x, v.y, v.z, v.w};
    #pragma unroll
    for (int j = 0; j < 4; ++j) {
        unsigned short h = f2bf(vv[j]);
        dh[tb + (size_t)(j4 + j) * 8] = h;
        if (SPLIT) dl[tb + (size_t)(j4 + j) * 8] = f2bf(vv[j] - bf2f(h));
    }
}

// ---------- codebook convert (tiled bf16 hi+lo, no transpose) + 0.5*||c||^2 ----------
__global__ __launch_bounds__(256) void k_conv_cb(
    const float* __restrict__ cb, unsigned short* __restrict__ ch,
    unsigned short* __restrict__ cl_, float* __restrict__ halfsq)
{
    const int t = threadIdx.x;
    const int ct = blockIdx.x;
    const int cl = t >> 4, f = t & 15;
    const int code = (ct << 4) + cl;
    float ssq = 0.f;
    #pragma unroll
    for (int it = 0; it < 4; ++it) {
        const int k4 = (f << 2) + (it << 6);
        float4 v = *(const float4*)(cb + (size_t)code * EMB + k4);
        ssq += v.x * v.x + v.y * v.y + v.z * v.z + v.w * v.w;
        size_t tb = ((size_t)(ct * 4 + (k4 >> 6))) * 1024 + ((k4 >> 3) & 7) * 128 + cl * 8 + (k4 & 7);
        ushort4 h = { f2bf(v.x), f2bf(v.y), f2bf(v.z), f2bf(v.w) };
        *(ushort4*)&ch[tb] = h;
        ushort4 lo = { f2bf(v.x - bf2f(h.x)), f2bf(v.y - bf2f(h.y)),
                       f2bf(v.z - bf2f(h.z)), f2bf(v.w - bf2f(h.w)) };
        *(ushort4*)&cl_[tb] = lo;
    }
    #pragma unroll
    for (int off = 1; off <= 8; off <<= 1) ssq += __shfl_xor(ssq, off);
    if (f == 0) halfsq[code] = 0.5f * ssq;
}

// ---------- generic MFMA layer: out = [relu](A @ B + bias)  (split-bf16 optional) ----------
template<int SPLIT>
__global__ __launch_bounds__(256) void k_layer(
    const float* __restrict__ A, int lda, int K,
    const unsigned short* __restrict__ Bh, const unsigned short* __restrict__ Bl,
    int b_nkt, const float* __restrict__ bias, int biasoff,
    float* __restrict__ out, int outw, int relu, int init)
{
    constexpr int AL = 8192;
    constexpr int BH = SPLIT ? 16384 : 8192;
    constexpr int BL = SPLIT ? 24576 : 8192;
    __shared__ __align__(16) unsigned short s_mem[SPLIT ? 32768 : 16384];

    const int t = threadIdx.x;
    const int m0 = blockIdx.x * 128;
    const int nb0 = blockIdx.y * 128;
    const int lane = t & 63, wv = t >> 6;
    const int wm = wv >> 1, wn = wv & 1;
    const int g = lane >> 4, rr = lane & 15;

    f32x4 acc[4][4];
    #pragma unroll
    for (int mi = 0; mi < 4; ++mi)
        #pragma unroll
        for (int ni = 0; ni < 4; ++ni) acc[mi][ni] = (f32x4){0.f, 0.f, 0.f, 0.f};

    for (int kc = 0; kc < K; kc += 64) {
        // ---- stage B first (async global->LDS, no VGPR round-trip)
        {
            const int ktile = kc >> 6;
            #pragma unroll
            for (int jj = 0; jj < 2; ++jj) {
                const int j = wv * 2 + jj;
                const size_t gt = ((size_t)(nb0 / 16 + j) * b_nkt + ktile) * 1024;
                #pragma unroll
                for (int half = 0; half < 2; ++half) {
                    gload16(Bh + gt + half * 512 + lane * 8,
                            &s_mem[BH + j * 1024 + half * 512]);
                    if (SPLIT)
                        gload16(Bl + gt + half * 512 + lane * 8,
                                &s_mem[BL + j * 1024 + half * 512]);
                }
            }
        }
        // ---- stage A (convert fp32 -> hi/lo bf16, XOR-swizzled fragment layout)
        #pragma unroll
        for (int it = 0; it < 8; ++it) {
            int f = t + (it << 8);
            int r = f >> 4, k4 = (f & 15) << 2;
            float4 v = *(const float4*)(A + (size_t)(m0 + r) * lda + kc + k4);
            int mt = r >> 4, rl = r & 15, kb = k4 >> 3, e = k4 & 7;
            int addr = mt * 1024 + kb * 128 + ((rl ^ kb) << 3) + e;
            ushort4 hi, lo;
            hi.x = f2bf(v.x); hi.y = f2bf(v.y); hi.z = f2bf(v.z); hi.w = f2bf(v.w);
            *(ushort4*)&s_mem[addr] = hi;
            if (SPLIT) {
                lo.x = f2bf(v.x - bf2f(hi.x)); lo.y = f2bf(v.y - bf2f(hi.y));
                lo.z = f2bf(v.z - bf2f(hi.z)); lo.w = f2bf(v.w - bf2f(hi.w));
                *(ushort4*)&s_mem[AL + addr] = lo;
            }
        }
        __syncthreads();
        #pragma unroll
        for (int s = 0; s < 2; ++s) {
            const int kb = (s << 2) + g;
            bf16x8 a_h[4], a_l[4], b_h[4], b_l[4];
            #pragma unroll
            for (int i = 0; i < 4; ++i) {
                int aaddr = (wm * 4 + i) * 1024 + kb * 128 + (((rr ^ kb) & 15) << 3);
                a_h[i] = *(const bf16x8*)&s_mem[aaddr];
                if (SPLIT) a_l[i] = *(const bf16x8*)&s_mem[AL + aaddr];
                int baddr = (wn * 4 + i) * 1024 + kb * 128 + (rr << 3);
                b_h[i] = *(const bf16x8*)&s_mem[BH + baddr];
                if (SPLIT) b_l[i] = *(const bf16x8*)&s_mem[BL + baddr];
            }
            #pragma unroll
            for (int mi = 0; mi < 4; ++mi)
                #pragma unroll
                for (int ni = 0; ni < 4; ++ni) {
                    acc[mi][ni] = __builtin_amdgcn_mfma_f32_16x16x32_bf16(a_h[mi], b_h[ni], acc[mi][ni], 0, 0, 0);
                    if (SPLIT) {
                        acc[mi][ni] = __builtin_amdgcn_mfma_f32_16x16x32_bf16(a_h[mi], b_l[ni], acc[mi][ni], 0, 0, 0);
                        acc[mi][ni] = __builtin_amdgcn_mfma_f32_16x16x32_bf16(a_l[mi], b_h[ni], acc[mi][ni], 0, 0, 0);
                    }
                }
        }
        __syncthreads();
    }
    float* sf = (float*)s_mem;
    for (int rm = 0; rm < 2; ++rm) {
        if (wm == rm) {
            #pragma unroll
            for (int mi = 0; mi < 4; ++mi)
                #pragma unroll
                for (int ni = 0; ni < 4; ++ni)
                    #pragma unroll
                    for (int rg = 0; rg < 4; ++rg)
                        sf[(mi * 16 + g * 4 + rg) * 128 + wn * 64 + ni * 16 + rr] = acc[mi][ni][rg];
        }
        __syncthreads();
        #pragma unroll
        for (int it = 0; it < 8; ++it) {
            int f = t + (it << 8);
            int r = f >> 5, c4 = (f & 31) << 2;
            float4 v = *(const float4*)&sf[r * 128 + c4];
            int gr = m0 + rm * 64 + r, gc = nb0 + c4;
            float* op = out + (size_t)gr * outw + gc;
            if (init) {
                v.x += bias[biasoff + gc + 0]; v.y += bias[biasoff + gc + 1];
                v.z += bias[biasoff + gc + 2]; v.w += bias[biasoff + gc + 3];
            } else {
                float4 o = *(const float4*)op;
                v.x += o.x; v.y += o.y; v.z += o.z; v.w += o.w;
            }
            if (relu) {
                v.x = fmaxf(v.x, 0.f); v.y = fmaxf(v.y, 0.f);
                v.z = fmaxf(v.z, 0.f); v.w = fmaxf(v.w, 0.f);
            }
            *(float4*)op = v;
        }
        __syncthreads();
    }
}

// ---------- distance argmin (split-bf16 MFMA + tight margin + fp32 rescore) + gather ----------
// 128 rows/block (512 blocks = 2/CU), 8 waves; each wave: 16 rows x all 64 codes of a chunk.
__global__ __launch_bounds__(512, 4) void k_dist(
    float* encq, const unsigned short* __restrict__ ch,
    const unsigned short* __restrict__ cl,
    const float* __restrict__ hsq, const float* __restrict__ cb)
{
    __shared__ __align__(16) unsigned short s_cb[32768];   // 64 KB: hi [0:16384), lo [16384:)
    __shared__ __align__(16) float s_erow[EMB];
    __shared__ int s_bi[128], s_need[128];
    __shared__ float s_wb[8]; __shared__ int s_wi[8];

    const int t = threadIdx.x;
    const int lane = t & 63, wv = t >> 6;      // wv = row-group 0..7
    const int g = lane >> 4, rr = lane & 15;
    const int r0 = blockIdx.x * 128;

    // e fragments hi+lo in registers, full K=256 (wave's 16 rows)
    bf16x8 eh[8], el[8];
    {
        const float* ep = encq + (size_t)(r0 + wv * 16 + rr) * EMB + g * 8;
        #pragma unroll
        for (int s = 0; s < 8; ++s) {
            float4 v0 = *(const float4*)(ep + s * 32);
            float4 v1 = *(const float4*)(ep + s * 32 + 4);
            float vv[8] = {v0.x, v0.y, v0.z, v0.w, v1.x, v1.y, v1.z, v1.w};
            bf16x8 a, b;
            #pragma unroll
            for (int j = 0; j < 8; ++j) {
                unsigned short h = f2bf(vv[j]);
                a[j] = (short)h;
                b[j] = (short)f2bf(vv[j] - bf2f(h));
            }
            eh[s] = a; el[s] = b;
        }
    }
    float bst[4] = {-1e30f, -1e30f, -1e30f, -1e30f};
    float sec[4] = {-1e30f, -1e30f, -1e30f, -1e30f};
    int bidx[4] = {0, 0, 0, 0};

    for (int chunk = 0; chunk < NCODE / 64; ++chunk) {
        __syncthreads();
        {   // stage 64 codes hi+lo via async global->LDS (each wave: 4 hi + 4 lo issues)
            const unsigned short* gh = ch + (size_t)chunk * 16384;
            const unsigned short* gl = cl + (size_t)chunk * 16384;
            #pragma unroll
            for (int i = 0; i < 4; ++i) {
                const int blk = wv * 4 + i;             // 0..31 x 512 ushorts
                gload16(gh + blk * 512 + lane * 8, &s_cb[blk * 512]);
                gload16(gl + blk * 512 + lane * 8, &s_cb[16384 + blk * 512]);
            }
        }
        __syncthreads();
        f32x4 acc[4];
        #pragma unroll
        for (int ci = 0; ci < 4; ++ci) acc[ci] = (f32x4){0.f, 0.f, 0.f, 0.f};
        #pragma unroll
        for (int s = 0; s < 8; ++s) {
            const int ktile = s >> 1, kb = ((s & 1) << 2) + g;
            #pragma unroll
            for (int ci = 0; ci < 4; ++ci) {
                const int off = (ci * 4 + ktile) * 1024 + kb * 128 + rr * 8;
                bf16x8 bh = *(const bf16x8*)&s_cb[off];
                bf16x8 bl = *(const bf16x8*)&s_cb[16384 + off];
                acc[ci] = __builtin_amdgcn_mfma_f32_16x16x32_bf16(eh[s], bh, acc[ci], 0, 0, 0);
                acc[ci] = __builtin_amdgcn_mfma_f32_16x16x32_bf16(eh[s], bl, acc[ci], 0, 0, 0);
                acc[ci] = __builtin_amdgcn_mfma_f32_16x16x32_bf16(el[s], bh, acc[ci], 0, 0, 0);
            }
        }
        #pragma unroll
        for (int ci = 0; ci < 4; ++ci) {
            const int code = (chunk << 6) + (ci << 4) + rr;
            const float hs = hsq[code];
            #pragma unroll
            for (int r2 = 0; r2 < 4; ++r2) {
                float v = acc[ci][r2] - hs;
                if (v > bst[r2]) { sec[r2] = bst[r2]; bst[r2] = v; bidx[r2] = code; }
                else if (v > sec[r2]) sec[r2] = v;
            }
        }
    }
    // intra-wave top-2 merge across the 16 code-lanes (lane bits 0..3)
    #pragma unroll
    for (int off = 1; off <= 8; off <<= 1) {
        #pragma unroll
        for (int r2 = 0; r2 < 4; ++r2) {
            float ob = __shfl_xor(bst[r2], off);
            float os2 = __shfl_xor(sec[r2], off);
            int oi = __shfl_xor(bidx[r2], off);
            if (ob > bst[r2] || (ob == bst[r2] && oi < bidx[r2])) {
                sec[r2] = fmaxf(bst[r2], fmaxf(sec[r2], os2));
                bst[r2] = ob; bidx[r2] = oi;
            } else {
                sec[r2] = fmaxf(sec[r2], fmaxf(ob, os2));
            }
        }
    }
    if (rr == 0) {
        #pragma unroll
        for (int r2 = 0; r2 < 4; ++r2) {
            int rl = wv * 16 + g * 4 + r2;
            s_bi[rl] = bidx[r2];
            s_need[rl] = (bst[r2] - sec[r2] <= 0.02f) ? 1 : 0;
        }
    }
    __syncthreads();
    // exact fp32 rescore for margin-flagged rows (uniform branch: s_need is shared)
    for (int r = 0; r < 128; ++r) {
        if (!s_need[r]) continue;
        if (t < 64) ((float4*)s_erow)[t] = ((const float4*)(encq + (size_t)(r0 + r) * EMB))[t];
        __syncthreads();
        float lb = -1e30f; int li = NCODE;
        for (int c = t; c < NCODE; c += 512) {
            const float4* cp = (const float4*)(cb + (size_t)c * EMB);
            float dot = 0.f;
            #pragma unroll 16
            for (int k = 0; k < 64; ++k) {
                float4 ev = ((const float4*)s_erow)[k];
                float4 cv = cp[k];
                dot += ev.x * cv.x + ev.y * cv.y + ev.z * cv.z + ev.w * cv.w;
            }
            float sc = dot - hsq[c];
            if (sc > lb || (sc == lb && c < li)) { lb = sc; li = c; }
        }
        #pragma unroll
        for (int off = 32; off >= 1; off >>= 1) {
            float ov = __shfl_down(lb, off); int oi = __shfl_down(li, off);
            if (ov > lb || (ov == lb && oi < li)) { lb = ov; li = oi; }
        }
        if (lane == 0) { s_wb[wv] = lb; s_wi[wv] = li; }
        __syncthreads();
        if (t == 0) {
            float b = s_wb[0]; int bi = s_wi[0];
            for (int w = 1; w < 8; ++w)
                if (s_wb[w] > b || (s_wb[w] == b && s_wi[w] < bi)) { b = s_wb[w]; bi = s_wi[w]; }
            s_bi[r] = bi;
        }
        __syncthreads();
    }
    __syncthreads();
    // gather: overwrite enc rows with cb[argmin]
    #pragma unroll
    for (int it = 0; it < 16; ++it) {
        int f = t + (it << 9);
        int row = f >> 6, c4 = (f & 63) << 2;
        int bi = s_bi[row];
        *(float4*)(encq + (size_t)(r0 + row) * EMB + c4) =
            *(const float4*)(cb + (size_t)bi * EMB + c4);
    }
}

// ---------- fallback fp32 decoder ----------
__global__ __launch_bounds__(256) void k_dec_fb(
    const float* __restrict__ qz,
    const float* __restrict__ W3, const float* __restrict__ b3,
    const float* __restrict__ W4, const float* __restrict__ b4,
    float* __restrict__ outd) {
    __shared__ float s_q[8][EMB];
    __shared__ float s_h2[8][HID];
    const int t = threadIdx.x;
    const int row0 = blockIdx.x * 8;
    #pragma unroll
    for (int r = 0; r < 8; ++r) s_q[r][t] = qz[(size_t)(row0 + r) * EMB + t];
    __syncthreads();
    for (int gg = 0; gg < 8; ++gg) {
        const int j = (gg << 8) + t;
        float acc[8];
        #pragma unroll
        for (int r = 0; r < 8; ++r) acc[r] = 0.f;
        const float* wp = W3 + j;
        for (int e = 0; e < EMB; e += 4) {
            const float w0 = wp[(size_t)(e + 0) * HID];
            const float w1v = wp[(size_t)(e + 1) * HID];
            const float w2v = wp[(size_t)(e + 2) * HID];
            const float w3v = wp[(size_t)(e + 3) * HID];
            #pragma unroll
            for (int r = 0; r < 8; ++r) {
                const float4 qv = *reinterpret_cast<const float4*>(&s_q[r][e]);
                acc[r] = fmaf(qv.x, w0, acc[r]);
                acc[r] = fmaf(qv.y, w1v, acc[r]);
                acc[r] = fmaf(qv.z, w2v, acc[r]);
                acc[r] = fmaf(qv.w, w3v, acc[r]);
            }
        }
        const float bb = b3[j];
        #pragma unroll
        for (int r = 0; r < 8; ++r) s_h2[r][j] = fmaxf(acc[r] + bb, 0.f);
    }
    __syncthreads();
    float acc4[8][4];
    #pragma unroll
    for (int r = 0; r < 8; ++r)
        #pragma unroll
        for (int ci = 0; ci < 4; ++ci) acc4[r][ci] = 0.f;
    const float* w4p = W4 + t;
    for (int k = 0; k < HID; k += 4) {
        float wv[4][4];
        #pragma unroll
        for (int ki = 0; ki < 4; ++ki)
            #pragma unroll
            for (int ci = 0; ci < 4; ++ci)
                wv[ki][ci] = w4p[(size_t)(k + ki) * IN_DIM + (ci << 8)];
        #pragma unroll
        for (int r = 0; r < 8; ++r) {
            const float4 hv = *reinterpret_cast<const float4*>(&s_h2[r][k]);
            #pragma unroll
            for (int ci = 0; ci < 4; ++ci) {
                acc4[r][ci] = fmaf(hv.x, wv[0][ci], acc4[r][ci]);
                acc4[r][ci] = fmaf(hv.y, wv[1][ci], acc4[r][ci]);
                acc4[r][ci] = fmaf(hv.z, wv[2][ci], acc4[r][ci]);
                acc4[r][ci] = fmaf(hv.w, wv[3][ci], acc4[r][ci]);
            }
        }
    }
    #pragma unroll
    for (int ci = 0; ci < 4; ++ci) {
        const float bb = b4[(ci << 8) + t];
        #pragma unroll
        for (int r = 0; r < 8; ++r)
            outd[(size_t)(row0 + r) * IN_DIM + (ci << 8) + t] = acc4[r][ci] + bb;
    }
}

extern "C" void kernel_launch(void* const* d_in, const int* in_sizes, int n_in,
                              void* d_out, int out_size, void* d_ws, size_t ws_size,
                              hipStream_t stream) {
    const float* x  = (const float*)d_in[0];
    const float* W1 = (const float*)d_in[1];
    const float* b1 = (const float*)d_in[2];
    const float* W2 = (const float*)d_in[3];
    const float* b2 = (const float*)d_in[4];
    const float* cb = (const float*)d_in[5];
    const float* W3 = (const float*)d_in[6];
    const float* b3 = (const float*)d_in[7];
    const float* W4 = (const float*)d_in[8];
    const float* b4 = (const float*)d_in[9];

    float* outq = (float*)d_out;                       // [N,256]
    float* outd = outq + (size_t)N_ROWS * EMB;         // [N,1024]

    // scratch in the decoded-output region (dead before decoder writes it)
    unsigned short* ou = (unsigned short*)outd;
    unsigned short* W1Th = ou;                         // 2M ushort
    unsigned short* W1Tl = ou + 2097152;               // 2M
    unsigned short* W2Th = ou + 4194304;               // 512K
    unsigned short* W2Tl = ou + 4718592;               // 512K
    unsigned short* cbh  = ou + 5242880;               // 1M
    unsigned short* cbl  = ou + 6291456;               // 1M
    float* halfsq = outd + 3670016;                    // 4K floats (after cbl)
    float* hbuf   = outd + 4194304;                    // N*512 fp32 (128 MiB)
    float* enc    = outq;                              // N*256 fp32, consumed by k_dist

    const bool fastdec = ws_size >= (size_t)139460608; // W3T(1M)+W4T(4M)+h2(128M)
    unsigned short* W3Th = (unsigned short*)d_ws;
    unsigned short* W4Th = W3Th + 524288;
    float* h2buf = (float*)((char*)d_ws + 5242880);

    // prep: weight/codebook conversion
    k_conv_w<1><<<dim3(128, 16), 256, 0, stream>>>(W1, W1Th, W1Tl, HID, 16);
    k_conv_w<1><<<dim3(16, 32), 256, 0, stream>>>(W2, W2Th, W2Tl, EMB, 32);
    k_conv_cb<<<256, 256, 0, stream>>>(cb, cbh, cbl, halfsq);
    if (fastdec) {
        k_conv_w<0><<<dim3(128, 4), 256, 0, stream>>>(W3, W3Th, nullptr, HID, 4);
        k_conv_w<0><<<dim3(64, 32), 256, 0, stream>>>(W4, W4Th, nullptr, IN_DIM, 32);
    }
    // encoder: split-bf16, hidden in quarters (h fp32 staged in outd)
    for (int q = 0; q < 4; ++q) {
        k_layer<1><<<dim3(512, 4), 256, 0, stream>>>(
            x, IN_DIM, IN_DIM, W1Th + (size_t)q * 524288, W1Tl + (size_t)q * 524288, 16,
            b1, q * 512, hbuf, 512, 1, 1);
        k_layer<1><<<dim3(512, 2), 256, 0, stream>>>(
            hbuf, 512, 512, W2Th + (size_t)q * 8192, W2Tl + (size_t)q * 8192, 32,
            b2, 0, enc, EMB, 0, q == 0);
    }
    // nearest-code + gather (writes quantized output in place)
    k_dist<<<512, 512, 0, stream>>>(enc, cbh, cbl, halfsq, cb);
    // decoder
    if (fastdec) {
        for (int q = 0; q < 4; ++q) {
            k_layer<0><<<dim3(512, 4), 256, 0, stream>>>(
                outq, EMB, EMB, W3Th + (size_t)q * 131072, nullptr, 4,
                b3, q * 512, h2buf, 512, 1, 1);
            k_layer<0><<<dim3(512, 8), 256, 0, stream>>>(
                h2buf, 512, 512, W4Th + (size_t)q * 8192, nullptr, 32,
                b4, 0, outd, IN_DIM, 0, q == 0);
        }
    } else {
        k_dec_fb<<<N_ROWS / 8, 256, 0, stream>>>(outq, W3, b3, W4, b4, outd);
    }
}

// Round 6
// 3529.243 us; speedup vs baseline: 4.6778x; 1.1049x over previous
//
#include <hip/hip_runtime.h>

#define N_ROWS 65536
#define IN_DIM 1024
#define HID    2048
#define EMB    256
#define NCODE  4096

typedef __attribute__((ext_vector_type(8))) short bf16x8;
typedef __attribute__((ext_vector_type(4))) float f32x4;

__device__ __forceinline__ unsigned short f2bf(float v) {
    unsigned u = __float_as_uint(v);
    u += 0x7FFFu + ((u >> 16) & 1u);
    return (unsigned short)(u >> 16);
}
__device__ __forceinline__ float bf2f(unsigned short h) {
    return __uint_as_float(((unsigned)h) << 16);
}
// async global->LDS 16B: per-lane global src, wave-uniform LDS base (+lane*16 by HW)
__device__ __forceinline__ void gload16(const unsigned short* g, unsigned short* l) {
    __builtin_amdgcn_global_load_lds(
        (const __attribute__((address_space(1))) unsigned int*)g,
        (__attribute__((address_space(3))) unsigned int*)l, 16, 0, 0);
}

// ---------- weight pre-convert (+transpose) into tiled fragment layout ----------
// src: [K][NC] fp32 row-major. dst: tiles (nt,kt), elem (rr,k) at
//   tile*1024 + ((k>>3)&7)*128 + rr*8 + (k&7)
template<int SPLIT>
__global__ __launch_bounds__(256) void k_conv_w(
    const float* __restrict__ src, unsigned short* __restrict__ dh,
    unsigned short* __restrict__ dl, int NC, int nkt)
{
    const int t = threadIdx.x;
    const int nt = blockIdx.x, kt = blockIdx.y;
    const int kk = t >> 2, j4 = (t & 3) << 2;
    const int k0 = kt << 6, n0 = nt << 4;
    float4 v = *(const float4*)(src + (size_t)(k0 + kk) * NC + n0 + j4);
    size_t tb = ((size_t)nt * nkt + kt) * 1024 + ((kk >> 3) * 128) + (kk & 7);
    float vv[4] = {v.x, v.y, v.z, v.w};
    #pragma unroll
    for (int j = 0; j < 4; ++j) {
        unsigned short h = f2bf(vv[j]);
        dh[tb + (size_t)(j4 + j) * 8] = h;
        if (SPLIT) dl[tb + (size_t)(j4 + j) * 8] = f2bf(vv[j] - bf2f(h));
    }
}

// ---------- codebook convert (tiled bf16 hi+lo) + 0.5*||c||^2 ----------
__global__ __launch_bounds__(256) void k_conv_cb(
    const float* __restrict__ cb, unsigned short* __restrict__ ch,
    unsigned short* __restrict__ cl_, float* __restrict__ halfsq)
{
    const int t = threadIdx.x;
    const int ct = blockIdx.x;
    const int cl = t >> 4, f = t & 15;
    const int code = (ct << 4) + cl;
    float ssq = 0.f;
    #pragma unroll
    for (int it = 0; it < 4; ++it) {
        const int k4 = (f << 2) + (it << 6);
        float4 v = *(const float4*)(cb + (size_t)code * EMB + k4);
        ssq += v.x * v.x + v.y * v.y + v.z * v.z + v.w * v.w;
        size_t tb = ((size_t)(ct * 4 + (k4 >> 6))) * 1024 + ((k4 >> 3) & 7) * 128 + cl * 8 + (k4 & 7);
        ushort4 h = { f2bf(v.x), f2bf(v.y), f2bf(v.z), f2bf(v.w) };
        *(ushort4*)&ch[tb] = h;
        ushort4 lo = { f2bf(v.x - bf2f(h.x)), f2bf(v.y - bf2f(h.y)),
                       f2bf(v.z - bf2f(h.z)), f2bf(v.w - bf2f(h.w)) };
        *(ushort4*)&cl_[tb] = lo;
    }
    #pragma unroll
    for (int off = 1; off <= 8; off <<= 1) ssq += __shfl_xor(ssq, off);
    if (f == 0) halfsq[code] = 0.5f * ssq;
}

// ---------- MFMA layer v2: BM=128, BN=256, BK=64, 512 thr (8 waves 2x4) ----------
// SPLIT: A,B split-bf16 (3-term). AFMT: 0 = A fp32 (convert in-kernel),
// 1 = A pre-tiled bf16 (gload16, a_nkt tiles per m-row-tile).
// OUTT: 0 = fp32 row-major out (+bias or +accumulate, relu), 1 = tiled bf16 out (strip nkt=8).
template<int SPLIT, int AFMT, int OUTT>
__global__ __launch_bounds__(512, 2) void k_layer2(
    const float* __restrict__ A, const unsigned short* __restrict__ At, int a_nkt,
    int lda, int K,
    const unsigned short* __restrict__ Bh, const unsigned short* __restrict__ Bl,
    int b_nkt, const float* __restrict__ bias, int biasoff,
    float* __restrict__ out, unsigned short* __restrict__ outt,
    int outw, int relu, int init)
{
    constexpr int AL = 8192;                    // A-lo (SPLIT only)
    constexpr int BH = SPLIT ? 16384 : 8192;
    constexpr int BL = SPLIT ? 32768 : 8192;    // unused when !SPLIT
    __shared__ __align__(16) unsigned short s_mem[SPLIT ? 49152 : 32768];

    const int t = threadIdx.x;
    const int m0 = blockIdx.x * 128;
    const int nb0 = blockIdx.y * 256;
    const int lane = t & 63, wv = t >> 6;
    const int wm = wv >> 2, wn = wv & 3;        // 2 x 4 waves, wave tile 64x64
    const int g = lane >> 4, rr = lane & 15;

    f32x4 acc[4][4];
    #pragma unroll
    for (int mi = 0; mi < 4; ++mi)
        #pragma unroll
        for (int ni = 0; ni < 4; ++ni) acc[mi][ni] = (f32x4){0.f, 0.f, 0.f, 0.f};

    for (int kc = 0; kc < K; kc += 64) {
        const int ktile = kc >> 6;
        // ---- stage B: 16 n-tiles, wave wv stages tiles {2wv, 2wv+1}
        #pragma unroll
        for (int jj = 0; jj < 2; ++jj) {
            const int j = wv * 2 + jj;
            const size_t gt = ((size_t)(nb0 / 16 + j) * b_nkt + ktile) * 1024;
            #pragma unroll
            for (int half = 0; half < 2; ++half) {
                gload16(Bh + gt + half * 512 + lane * 8,
                        &s_mem[BH + j * 1024 + half * 512]);
                if (SPLIT)
                    gload16(Bl + gt + half * 512 + lane * 8,
                            &s_mem[BL + j * 1024 + half * 512]);
            }
        }
        // ---- stage A
        if (AFMT == 0) {
            #pragma unroll
            for (int it = 0; it < 4; ++it) {
                int f = t + (it << 9);
                int r = f >> 4, k4 = (f & 15) << 2;
                float4 v = *(const float4*)(A + (size_t)(m0 + r) * lda + kc + k4);
                int mt = r >> 4, rl = r & 15, kb = k4 >> 3, e = k4 & 7;
                int addr = mt * 1024 + kb * 128 + ((rl ^ kb) << 3) + e;
                ushort4 hi, lo;
                hi.x = f2bf(v.x); hi.y = f2bf(v.y); hi.z = f2bf(v.z); hi.w = f2bf(v.w);
                *(ushort4*)&s_mem[addr] = hi;
                if (SPLIT) {
                    lo.x = f2bf(v.x - bf2f(hi.x)); lo.y = f2bf(v.y - bf2f(hi.y));
                    lo.z = f2bf(v.z - bf2f(hi.z)); lo.w = f2bf(v.w - bf2f(hi.w));
                    *(ushort4*)&s_mem[AL + addr] = lo;
                }
            }
        } else {
            // pre-tiled A: wave wv stages m-tile wv (linear)
            const size_t gt = ((size_t)(m0 / 16 + wv) * a_nkt + ktile) * 1024;
            #pragma unroll
            for (int half = 0; half < 2; ++half)
                gload16(At + gt + half * 512 + lane * 8,
                        &s_mem[wv * 1024 + half * 512]);
        }
        __syncthreads();
        // ---- compute
        #pragma unroll
        for (int s = 0; s < 2; ++s) {
            const int kb = (s << 2) + g;
            bf16x8 a_h[4], a_l[4], b_h[4], b_l[4];
            #pragma unroll
            for (int i = 0; i < 4; ++i) {
                int arow = (AFMT == 0) ? (((rr ^ kb) & 15) << 3) : (rr << 3);
                int aaddr = (wm * 4 + i) * 1024 + kb * 128 + arow;
                a_h[i] = *(const bf16x8*)&s_mem[aaddr];
                if (SPLIT) a_l[i] = *(const bf16x8*)&s_mem[AL + aaddr];
                int baddr = (wn * 4 + i) * 1024 + kb * 128 + (rr << 3);
                b_h[i] = *(const bf16x8*)&s_mem[BH + baddr];
                if (SPLIT) b_l[i] = *(const bf16x8*)&s_mem[BL + baddr];
            }
            #pragma unroll
            for (int mi = 0; mi < 4; ++mi)
                #pragma unroll
                for (int ni = 0; ni < 4; ++ni) {
                    acc[mi][ni] = __builtin_amdgcn_mfma_f32_16x16x32_bf16(a_h[mi], b_h[ni], acc[mi][ni], 0, 0, 0);
                    if (SPLIT) {
                        acc[mi][ni] = __builtin_amdgcn_mfma_f32_16x16x32_bf16(a_h[mi], b_l[ni], acc[mi][ni], 0, 0, 0);
                        acc[mi][ni] = __builtin_amdgcn_mfma_f32_16x16x32_bf16(a_l[mi], b_h[ni], acc[mi][ni], 0, 0, 0);
                    }
                }
        }
        __syncthreads();
    }

    if (OUTT == 0) {
        // fp32 row-major epilogue via LDS bounce (two 64-row passes)
        float* sf = (float*)s_mem;
        for (int rm = 0; rm < 2; ++rm) {
            if (wm == rm) {
                #pragma unroll
                for (int mi = 0; mi < 4; ++mi)
                    #pragma unroll
                    for (int ni = 0; ni < 4; ++ni)
                        #pragma unroll
                        for (int rg = 0; rg < 4; ++rg)
                            sf[(mi * 16 + g * 4 + rg) * 256 + wn * 64 + ni * 16 + rr] = acc[mi][ni][rg];
            }
            __syncthreads();
            #pragma unroll
            for (int it = 0; it < 8; ++it) {
                int f = t + (it << 9);
                int r = f >> 6, c4 = (f & 63) << 2;
                float4 v = *(const float4*)&sf[r * 256 + c4];
                int gr = m0 + rm * 64 + r, gc = nb0 + c4;
                float* op = out + (size_t)gr * outw + gc;
                if (init) {
                    v.x += bias[biasoff + gc + 0]; v.y += bias[biasoff + gc + 1];
                    v.z += bias[biasoff + gc + 2]; v.w += bias[biasoff + gc + 3];
                } else {
                    float4 o = *(const float4*)op;
                    v.x += o.x; v.y += o.y; v.z += o.z; v.w += o.w;
                }
                if (relu) {
                    v.x = fmaxf(v.x, 0.f); v.y = fmaxf(v.y, 0.f);
                    v.z = fmaxf(v.z, 0.f); v.w = fmaxf(v.w, 0.f);
                }
                *(float4*)op = v;
            }
            __syncthreads();
        }
    } else {
        // tiled bf16 epilogue (A-fragment layout for the next GEMM; strip nkt = 8)
        #pragma unroll
        for (int mi = 0; mi < 4; ++mi)
            #pragma unroll
            for (int ni = 0; ni < 4; ++ni) {
                const int c = wn * 64 + ni * 16 + rr;
                float bb = bias[biasoff + nb0 + c];
                #pragma unroll
                for (int rg = 0; rg < 4; ++rg) {
                    float v = acc[mi][ni][rg] + bb;
                    if (relu) v = fmaxf(v, 0.f);
                    int addr = ((wm * 4 + mi) * 4 + wn) * 1024
                             + (ni * 2 + (rr >> 3)) * 128 + (g * 4 + rg) * 8 + (rr & 7);
                    s_mem[addr] = f2bf(v);
                }
            }
        __syncthreads();
        #pragma unroll
        for (int it = 0; it < 8; ++it) {
            int f = t + (it << 9);
            int tl = f >> 7, w8 = f & 127;
            size_t gaddr = ((size_t)(m0 / 16 + (tl >> 2)) * 8 + nb0 / 64 + (tl & 3)) * 1024;
            *(float4*)(outt + gaddr + w8 * 8) = *(const float4*)&s_mem[tl * 1024 + w8 * 8];
        }
    }
}

// ---------- distance argmin (split-bf16 MFMA, reg-prefetch pipeline) + gather ----------
// 128 rows/block, 512 blocks, 8 waves. Chunk k+1 prefetched to VGPRs during chunk k compute.
__global__ __launch_bounds__(512, 2) void k_dist(
    float* encq, const unsigned short* __restrict__ ch,
    const unsigned short* __restrict__ cl,
    const float* __restrict__ hsq, const float* __restrict__ cb)
{
    __shared__ __align__(16) unsigned short s_cb[32768];   // 64 KB: hi [0:16384), lo [16384:)
    __shared__ __align__(16) float s_erow[EMB];
    __shared__ int s_bi[128], s_need[128];
    __shared__ float s_wb[8]; __shared__ int s_wi[8];

    const int t = threadIdx.x;
    const int lane = t & 63, wv = t >> 6;
    const int g = lane >> 4, rr = lane & 15;
    const int r0 = blockIdx.x * 128;

    // e fragments hi+lo in registers, full K=256 (wave's 16 rows)
    bf16x8 eh[8], el[8];
    {
        const float* ep = encq + (size_t)(r0 + wv * 16 + rr) * EMB + g * 8;
        #pragma unroll
        for (int s = 0; s < 8; ++s) {
            float4 v0 = *(const float4*)(ep + s * 32);
            float4 v1 = *(const float4*)(ep + s * 32 + 4);
            float vv[8] = {v0.x, v0.y, v0.z, v0.w, v1.x, v1.y, v1.z, v1.w};
            bf16x8 a, b;
            #pragma unroll
            for (int j = 0; j < 8; ++j) {
                unsigned short h = f2bf(vv[j]);
                a[j] = (short)h;
                b[j] = (short)f2bf(vv[j] - bf2f(h));
            }
            eh[s] = a; el[s] = b;
        }
    }
    float bst[4] = {-1e30f, -1e30f, -1e30f, -1e30f};
    float sec[4] = {-1e30f, -1e30f, -1e30f, -1e30f};
    int bidx[4] = {0, 0, 0, 0};

    // prologue: stage chunk 0 via async DMA (drained by first __syncthreads)
    #pragma unroll
    for (int i = 0; i < 4; ++i) {
        const int blk = wv * 4 + i;
        gload16(ch + blk * 512 + lane * 8, &s_cb[blk * 512]);
        gload16(cl + blk * 512 + lane * 8, &s_cb[16384 + blk * 512]);
    }

    for (int chunk = 0; chunk < NCODE / 64; ++chunk) {
        // prefetch chunk+1 (wrapped) to registers — latency hides under compute
        const int nc = (chunk + 1) & 63;
        const unsigned short* gh = ch + (size_t)nc * 16384;
        const unsigned short* gl = cl + (size_t)nc * 16384;
        bf16x8 ph[4], pl[4];
        #pragma unroll
        for (int rd = 0; rd < 4; ++rd) {
            ph[rd] = *(const bf16x8*)(gh + (size_t)(t + (rd << 9)) * 8);
            pl[rd] = *(const bf16x8*)(gl + (size_t)(t + (rd << 9)) * 8);
        }
        __syncthreads();                         // chunk's LDS ready
        f32x4 acc[4];
        #pragma unroll
        for (int ci = 0; ci < 4; ++ci) acc[ci] = (f32x4){0.f, 0.f, 0.f, 0.f};
        #pragma unroll
        for (int s = 0; s < 8; ++s) {
            const int ktile = s >> 1, kb = ((s & 1) << 2) + g;
            #pragma unroll
            for (int ci = 0; ci < 4; ++ci) {
                const int off = (ci * 4 + ktile) * 1024 + kb * 128 + rr * 8;
                bf16x8 bh = *(const bf16x8*)&s_cb[off];
                bf16x8 bl = *(const bf16x8*)&s_cb[16384 + off];
                acc[ci] = __builtin_amdgcn_mfma_f32_16x16x32_bf16(eh[s], bh, acc[ci], 0, 0, 0);
                acc[ci] = __builtin_amdgcn_mfma_f32_16x16x32_bf16(eh[s], bl, acc[ci], 0, 0, 0);
                acc[ci] = __builtin_amdgcn_mfma_f32_16x16x32_bf16(el[s], bh, acc[ci], 0, 0, 0);
            }
        }
        #pragma unroll
        for (int ci = 0; ci < 4; ++ci) {
            const int code = (chunk << 6) + (ci << 4) + rr;
            const float hs = hsq[code];
            #pragma unroll
            for (int r2 = 0; r2 < 4; ++r2) {
                float v = acc[ci][r2] - hs;
                if (v > bst[r2]) { sec[r2] = bst[r2]; bst[r2] = v; bidx[r2] = code; }
                else if (v > sec[r2]) sec[r2] = v;
            }
        }
        __syncthreads();                         // all waves done reading s_cb
        #pragma unroll
        for (int rd = 0; rd < 4; ++rd) {
            *(bf16x8*)&s_cb[(t + (rd << 9)) * 8] = ph[rd];
            *(bf16x8*)&s_cb[16384 + (t + (rd << 9)) * 8] = pl[rd];
        }
    }
    // intra-wave top-2 merge across the 16 code-lanes
    #pragma unroll
    for (int off = 1; off <= 8; off <<= 1) {
        #pragma unroll
        for (int r2 = 0; r2 < 4; ++r2) {
            float ob = __shfl_xor(bst[r2], off);
            float os2 = __shfl_xor(sec[r2], off);
            int oi = __shfl_xor(bidx[r2], off);
            if (ob > bst[r2] || (ob == bst[r2] && oi < bidx[r2])) {
                sec[r2] = fmaxf(bst[r2], fmaxf(sec[r2], os2));
                bst[r2] = ob; bidx[r2] = oi;
            } else {
                sec[r2] = fmaxf(sec[r2], fmaxf(ob, os2));
            }
        }
    }
    if (rr == 0) {
        #pragma unroll
        for (int r2 = 0; r2 < 4; ++r2) {
            int rl = wv * 16 + g * 4 + r2;
            s_bi[rl] = bidx[r2];
            s_need[rl] = (bst[r2] - sec[r2] <= 0.02f) ? 1 : 0;
        }
    }
    __syncthreads();
    // exact fp32 rescore for margin-flagged rows (uniform branch: s_need is shared)
    for (int r = 0; r < 128; ++r) {
        if (!s_need[r]) continue;
        if (t < 64) ((float4*)s_erow)[t] = ((const float4*)(encq + (size_t)(r0 + r) * EMB))[t];
        __syncthreads();
        float lb = -1e30f; int li = NCODE;
        for (int c = t; c < NCODE; c += 512) {
            const float4* cp = (const float4*)(cb + (size_t)c * EMB);
            float dot = 0.f;
            #pragma unroll 16
            for (int k = 0; k < 64; ++k) {
                float4 ev = ((const float4*)s_erow)[k];
                float4 cv = cp[k];
                dot += ev.x * cv.x + ev.y * cv.y + ev.z * cv.z + ev.w * cv.w;
            }
            float sc = dot - hsq[c];
            if (sc > lb || (sc == lb && c < li)) { lb = sc; li = c; }
        }
        #pragma unroll
        for (int off = 32; off >= 1; off >>= 1) {
            float ov = __shfl_down(lb, off); int oi = __shfl_down(li, off);
            if (ov > lb || (ov == lb && oi < li)) { lb = ov; li = oi; }
        }
        if (lane == 0) { s_wb[wv] = lb; s_wi[wv] = li; }
        __syncthreads();
        if (t == 0) {
            float b = s_wb[0]; int bi = s_wi[0];
            for (int w = 1; w < 8; ++w)
                if (s_wb[w] > b || (s_wb[w] == b && s_wi[w] < bi)) { b = s_wb[w]; bi = s_wi[w]; }
            s_bi[r] = bi;
        }
        __syncthreads();
    }
    __syncthreads();
    // gather: overwrite enc rows with cb[argmin]
    #pragma unroll
    for (int it = 0; it < 16; ++it) {
        int f = t + (it << 9);
        int row = f >> 6, c4 = (f & 63) << 2;
        int bi = s_bi[row];
        *(float4*)(encq + (size_t)(r0 + row) * EMB + c4) =
            *(const float4*)(cb + (size_t)bi * EMB + c4);
    }
}

// ---------- fallback fp32 decoder ----------
__global__ __launch_bounds__(256) void k_dec_fb(
    const float* __restrict__ qz,
    const float* __restrict__ W3, const float* __restrict__ b3,
    const float* __restrict__ W4, const float* __restrict__ b4,
    float* __restrict__ outd) {
    __shared__ float s_q[8][EMB];
    __shared__ float s_h2[8][HID];
    const int t = threadIdx.x;
    const int row0 = blockIdx.x * 8;
    #pragma unroll
    for (int r = 0; r < 8; ++r) s_q[r][t] = qz[(size_t)(row0 + r) * EMB + t];
    __syncthreads();
    for (int gg = 0; gg < 8; ++gg) {
        const int j = (gg << 8) + t;
        float acc[8];
        #pragma unroll
        for (int r = 0; r < 8; ++r) acc[r] = 0.f;
        const float* wp = W3 + j;
        for (int e = 0; e < EMB; e += 4) {
            const float w0 = wp[(size_t)(e + 0) * HID];
            const float w1v = wp[(size_t)(e + 1) * HID];
            const float w2v = wp[(size_t)(e + 2) * HID];
            const float w3v = wp[(size_t)(e + 3) * HID];
            #pragma unroll
            for (int r = 0; r < 8; ++r) {
                const float4 qv = *reinterpret_cast<const float4*>(&s_q[r][e]);
                acc[r] = fmaf(qv.x, w0, acc[r]);
                acc[r] = fmaf(qv.y, w1v, acc[r]);
                acc[r] = fmaf(qv.z, w2v, acc[r]);
                acc[r] = fmaf(qv.w, w3v, acc[r]);
            }
        }
        const float bb = b3[j];
        #pragma unroll
        for (int r = 0; r < 8; ++r) s_h2[r][j] = fmaxf(acc[r] + bb, 0.f);
    }
    __syncthreads();
    float acc4[8][4];
    #pragma unroll
    for (int r = 0; r < 8; ++r)
        #pragma unroll
        for (int ci = 0; ci < 4; ++ci) acc4[r][ci] = 0.f;
    const float* w4p = W4 + t;
    for (int k = 0; k < HID; k += 4) {
        float wv[4][4];
        #pragma unroll
        for (int ki = 0; ki < 4; ++ki)
            #pragma unroll
            for (int ci = 0; ci < 4; ++ci)
                wv[ki][ci] = w4p[(size_t)(k + ki) * IN_DIM + (ci << 8)];
        #pragma unroll
        for (int r = 0; r < 8; ++r) {
            const float4 hv = *reinterpret_cast<const float4*>(&s_h2[r][k]);
            #pragma unroll
            for (int ci = 0; ci < 4; ++ci) {
                acc4[r][ci] = fmaf(hv.x, wv[0][ci], acc4[r][ci]);
                acc4[r][ci] = fmaf(hv.y, wv[1][ci], acc4[r][ci]);
                acc4[r][ci] = fmaf(hv.z, wv[2][ci], acc4[r][ci]);
                acc4[r][ci] = fmaf(hv.w, wv[3][ci], acc4[r][ci]);
            }
        }
    }
    #pragma unroll
    for (int ci = 0; ci < 4; ++ci) {
        const float bb = b4[(ci << 8) + t];
        #pragma unroll
        for (int r = 0; r < 8; ++r)
            outd[(size_t)(row0 + r) * IN_DIM + (ci << 8) + t] = acc4[r][ci] + bb;
    }
}

extern "C" void kernel_launch(void* const* d_in, const int* in_sizes, int n_in,
                              void* d_out, int out_size, void* d_ws, size_t ws_size,
                              hipStream_t stream) {
    const float* x  = (const float*)d_in[0];
    const float* W1 = (const float*)d_in[1];
    const float* b1 = (const float*)d_in[2];
    const float* W2 = (const float*)d_in[3];
    const float* b2 = (const float*)d_in[4];
    const float* cb = (const float*)d_in[5];
    const float* W3 = (const float*)d_in[6];
    const float* b3 = (const float*)d_in[7];
    const float* W4 = (const float*)d_in[8];
    const float* b4 = (const float*)d_in[9];

    float* outq = (float*)d_out;                       // [N,256]
    float* outd = outq + (size_t)N_ROWS * EMB;         // [N,1024]

    // scratch in the decoded-output region (dead before GEMM4 writes it)
    unsigned short* ou = (unsigned short*)outd;
    unsigned short* W1Th = ou;                         // 2M ushort
    unsigned short* W1Tl = ou + 2097152;               // 2M
    unsigned short* W2Th = ou + 4194304;               // 512K
    unsigned short* W2Tl = ou + 4718592;               // 512K
    unsigned short* cbh  = ou + 5242880;               // 1M
    unsigned short* cbl  = ou + 6291456;               // 1M
    float* halfsq = outd + 3670016;                    // 4K floats (after cbl)
    float* hbuf   = outd + 4194304;                    // N*512 fp32 (128 MiB)
    float* enc    = outq;                              // N*256 fp32, consumed by k_dist

    // d_ws: W3T (1MB) + W4T (4MB) + h2t strip (tiled bf16, 64MB)
    const bool fastdec = ws_size >= (size_t)72351744;
    unsigned short* W3Th = (unsigned short*)d_ws;
    unsigned short* W4Th = W3Th + 524288;
    unsigned short* h2t  = (unsigned short*)((char*)d_ws + 5242880);

    // prep: weight/codebook conversion
    k_conv_w<1><<<dim3(128, 16), 256, 0, stream>>>(W1, W1Th, W1Tl, HID, 16);
    k_conv_w<1><<<dim3(16, 32), 256, 0, stream>>>(W2, W2Th, W2Tl, EMB, 32);
    k_conv_cb<<<256, 256, 0, stream>>>(cb, cbh, cbl, halfsq);
    if (fastdec) {
        k_conv_w<0><<<dim3(128, 4), 256, 0, stream>>>(W3, W3Th, nullptr, HID, 4);
        k_conv_w<0><<<dim3(64, 32), 256, 0, stream>>>(W4, W4Th, nullptr, IN_DIM, 32);
    }
    // encoder: split-bf16, hidden quarters (h fp32 strip in outd)
    for (int q = 0; q < 4; ++q) {
        k_layer2<1, 0, 0><<<dim3(512, 2), 512, 0, stream>>>(
            x, nullptr, 0, IN_DIM, IN_DIM,
            W1Th + (size_t)q * 524288, W1Tl + (size_t)q * 524288, 16,
            b1, q * 512, hbuf, nullptr, 512, 1, 1);
        k_layer2<1, 0, 0><<<dim3(512, 1), 512, 0, stream>>>(
            hbuf, nullptr, 0, 512, 512,
            W2Th + (size_t)q * 8192, W2Tl + (size_t)q * 8192, 32,
            b2, 0, enc, nullptr, EMB, 0, q == 0);
    }
    // nearest-code + gather (writes quantized output in place)
    k_dist<<<512, 512, 0, stream>>>(enc, cbh, cbl, halfsq, cb);
    // decoder
    if (fastdec) {
        for (int q = 0; q < 4; ++q) {
            // GEMM3: h2 strip = relu(q @ W3q + b3q) -> tiled bf16
            k_layer2<0, 0, 1><<<dim3(512, 2), 512, 0, stream>>>(
                outq, nullptr, 0, EMB, EMB,
                W3Th + (size_t)q * 131072, nullptr, 4,
                b3, q * 512, nullptr, h2t, 0, 1, 0);
            // GEMM4: outd (+)= h2 strip @ W4q (+ b4 on first)
            k_layer2<0, 1, 0><<<dim3(512, 4), 512, 0, stream>>>(
                nullptr, h2t, 8, 0, 512,
                W4Th + (size_t)q * 8192, nullptr, 32,
                b4, 0, outd, nullptr, IN_DIM, 0, q == 0);
        }
    } else {
        k_dec_fb<<<N_ROWS / 8, 256, 0, stream>>>(outq, W3, b3, W4, b4, outd);
    }
}

// Round 7
// 3299.209 us; speedup vs baseline: 5.0040x; 1.0697x over previous
//
#include <hip/hip_runtime.h>

#define N_ROWS 65536
#define IN_DIM 1024
#define HID    2048
#define EMB    256
#define NCODE  4096

typedef __attribute__((ext_vector_type(8))) short bf16x8;
typedef __attribute__((ext_vector_type(4))) float f32x4;

__device__ __forceinline__ unsigned short f2bf(float v) {
    unsigned u = __float_as_uint(v);
    u += 0x7FFFu + ((u >> 16) & 1u);
    return (unsigned short)(u >> 16);
}
__device__ __forceinline__ float bf2f(unsigned short h) {
    return __uint_as_float(((unsigned)h) << 16);
}
// async global->LDS 16B: per-lane global src, wave-uniform LDS base (+lane*16 by HW)
__device__ __forceinline__ void gload16(const unsigned short* g, unsigned short* l) {
    __builtin_amdgcn_global_load_lds(
        (const __attribute__((address_space(1))) unsigned int*)g,
        (__attribute__((address_space(3))) unsigned int*)l, 16, 0, 0);
}

// ---------- weight pre-convert (+transpose) into tiled fragment layout ----------
// src: [K][NC] fp32 row-major. dst: tiles (nt,kt), elem (rr,k) at
//   tile*1024 + ((k>>3)&7)*128 + rr*8 + (k&7)
template<int SPLIT>
__global__ __launch_bounds__(256) void k_conv_w(
    const float* __restrict__ src, unsigned short* __restrict__ dh,
    unsigned short* __restrict__ dl, int NC, int nkt)
{
    const int t = threadIdx.x;
    const int nt = blockIdx.x, kt = blockIdx.y;
    const int kk = t >> 2, j4 = (t & 3) << 2;
    const int k0 = kt << 6, n0 = nt << 4;
    float4 v = *(const float4*)(src + (size_t)(k0 + kk) * NC + n0 + j4);
    size_t tb = ((size_t)nt * nkt + kt) * 1024 + ((kk >> 3) * 128) + (kk & 7);
    float vv[4] = {v.x, v.y, v.z, v.w};
    #pragma unroll
    for (int j = 0; j < 4; ++j) {
        unsigned short h = f2bf(vv[j]);
        dh[tb + (size_t)(j4 + j) * 8] = h;
        if (SPLIT) dl[tb + (size_t)(j4 + j) * 8] = f2bf(vv[j] - bf2f(h));
    }
}

// ---------- codebook convert (tiled bf16 hi+lo) + 0.5*||c||^2 ----------
__global__ __launch_bounds__(256) void k_conv_cb(
    const float* __restrict__ cb, unsigned short* __restrict__ ch,
    unsigned short* __restrict__ cl_, float* __restrict__ halfsq)
{
    const int t = threadIdx.x;
    const int ct = blockIdx.x;
    const int cl = t >> 4, f = t & 15;
    const int code = (ct << 4) + cl;
    float ssq = 0.f;
    #pragma unroll
    for (int it = 0; it < 4; ++it) {
        const int k4 = (f << 2) + (it << 6);
        float4 v = *(const float4*)(cb + (size_t)code * EMB + k4);
        ssq += v.x * v.x + v.y * v.y + v.z * v.z + v.w * v.w;
        size_t tb = ((size_t)(ct * 4 + (k4 >> 6))) * 1024 + ((k4 >> 3) & 7) * 128 + cl * 8 + (k4 & 7);
        ushort4 h = { f2bf(v.x), f2bf(v.y), f2bf(v.z), f2bf(v.w) };
        *(ushort4*)&ch[tb] = h;
        ushort4 lo = { f2bf(v.x - bf2f(h.x)), f2bf(v.y - bf2f(h.y)),
                       f2bf(v.z - bf2f(h.z)), f2bf(v.w - bf2f(h.w)) };
        *(ushort4*)&cl_[tb] = lo;
    }
    #pragma unroll
    for (int off = 1; off <= 8; off <<= 1) ssq += __shfl_xor(ssq, off);
    if (f == 0) halfsq[code] = 0.5f * ssq;
}

// ---------- MFMA layer v2: BM=128, BN=256, BK=64, 512 thr (8 waves 2x4) ----------
// SPLIT: A,B split-bf16 (3-term). AFMT: 0 = A fp32 (convert in-kernel),
// 1 = A pre-tiled bf16 (gload16, a_nkt tiles per m-row-tile).
// OUTT: 0 = fp32 row-major out (+bias or +accumulate, relu), outw = row width;
//       1 = tiled bf16 out, outw = out_nkt (k-tiles per m-tile row).
template<int SPLIT, int AFMT, int OUTT>
__global__ __launch_bounds__(512, 2) void k_layer2(
    const float* __restrict__ A, const unsigned short* __restrict__ At, int a_nkt,
    int lda, int K,
    const unsigned short* __restrict__ Bh, const unsigned short* __restrict__ Bl,
    int b_nkt, const float* __restrict__ bias, int biasoff,
    float* __restrict__ out, unsigned short* __restrict__ outt,
    int outw, int relu, int init)
{
    constexpr int AL = 8192;                    // A-lo (SPLIT only)
    constexpr int BH = SPLIT ? 16384 : 8192;
    constexpr int BL = SPLIT ? 32768 : 8192;    // unused when !SPLIT
    __shared__ __align__(16) unsigned short s_mem[SPLIT ? 49152 : 32768];

    const int t = threadIdx.x;
    const int m0 = blockIdx.x * 128;
    const int nb0 = blockIdx.y * 256;
    const int lane = t & 63, wv = t >> 6;
    const int wm = wv >> 2, wn = wv & 3;        // 2 x 4 waves, wave tile 64x64
    const int g = lane >> 4, rr = lane & 15;

    f32x4 acc[4][4];
    #pragma unroll
    for (int mi = 0; mi < 4; ++mi)
        #pragma unroll
        for (int ni = 0; ni < 4; ++ni) acc[mi][ni] = (f32x4){0.f, 0.f, 0.f, 0.f};

    for (int kc = 0; kc < K; kc += 64) {
        const int ktile = kc >> 6;
        // ---- stage B: 16 n-tiles, wave wv stages tiles {2wv, 2wv+1}
        #pragma unroll
        for (int jj = 0; jj < 2; ++jj) {
            const int j = wv * 2 + jj;
            const size_t gt = ((size_t)(nb0 / 16 + j) * b_nkt + ktile) * 1024;
            #pragma unroll
            for (int half = 0; half < 2; ++half) {
                gload16(Bh + gt + half * 512 + lane * 8,
                        &s_mem[BH + j * 1024 + half * 512]);
                if (SPLIT)
                    gload16(Bl + gt + half * 512 + lane * 8,
                            &s_mem[BL + j * 1024 + half * 512]);
            }
        }
        // ---- stage A
        if (AFMT == 0) {
            #pragma unroll
            for (int it = 0; it < 4; ++it) {
                int f = t + (it << 9);
                int r = f >> 4, k4 = (f & 15) << 2;
                float4 v = *(const float4*)(A + (size_t)(m0 + r) * lda + kc + k4);
                int mt = r >> 4, rl = r & 15, kb = k4 >> 3, e = k4 & 7;
                int addr = mt * 1024 + kb * 128 + ((rl ^ kb) << 3) + e;
                ushort4 hi, lo;
                hi.x = f2bf(v.x); hi.y = f2bf(v.y); hi.z = f2bf(v.z); hi.w = f2bf(v.w);
                *(ushort4*)&s_mem[addr] = hi;
                if (SPLIT) {
                    lo.x = f2bf(v.x - bf2f(hi.x)); lo.y = f2bf(v.y - bf2f(hi.y));
                    lo.z = f2bf(v.z - bf2f(hi.z)); lo.w = f2bf(v.w - bf2f(hi.w));
                    *(ushort4*)&s_mem[AL + addr] = lo;
                }
            }
        } else {
            const size_t gt = ((size_t)(m0 / 16 + wv) * a_nkt + ktile) * 1024;
            #pragma unroll
            for (int half = 0; half < 2; ++half)
                gload16(At + gt + half * 512 + lane * 8,
                        &s_mem[wv * 1024 + half * 512]);
        }
        __syncthreads();
        // ---- compute
        __builtin_amdgcn_s_setprio(1);
        #pragma unroll
        for (int s = 0; s < 2; ++s) {
            const int kb = (s << 2) + g;
            bf16x8 a_h[4], a_l[4], b_h[4], b_l[4];
            #pragma unroll
            for (int i = 0; i < 4; ++i) {
                int arow = (AFMT == 0) ? (((rr ^ kb) & 15) << 3) : (rr << 3);
                int aaddr = (wm * 4 + i) * 1024 + kb * 128 + arow;
                a_h[i] = *(const bf16x8*)&s_mem[aaddr];
                if (SPLIT) a_l[i] = *(const bf16x8*)&s_mem[AL + aaddr];
                int baddr = (wn * 4 + i) * 1024 + kb * 128 + (rr << 3);
                b_h[i] = *(const bf16x8*)&s_mem[BH + baddr];
                if (SPLIT) b_l[i] = *(const bf16x8*)&s_mem[BL + baddr];
            }
            #pragma unroll
            for (int mi = 0; mi < 4; ++mi)
                #pragma unroll
                for (int ni = 0; ni < 4; ++ni) {
                    acc[mi][ni] = __builtin_amdgcn_mfma_f32_16x16x32_bf16(a_h[mi], b_h[ni], acc[mi][ni], 0, 0, 0);
                    if (SPLIT) {
                        acc[mi][ni] = __builtin_amdgcn_mfma_f32_16x16x32_bf16(a_h[mi], b_l[ni], acc[mi][ni], 0, 0, 0);
                        acc[mi][ni] = __builtin_amdgcn_mfma_f32_16x16x32_bf16(a_l[mi], b_h[ni], acc[mi][ni], 0, 0, 0);
                    }
                }
        }
        __builtin_amdgcn_s_setprio(0);
        __syncthreads();
    }

    if (OUTT == 0) {
        float* sf = (float*)s_mem;
        for (int rm = 0; rm < 2; ++rm) {
            if (wm == rm) {
                #pragma unroll
                for (int mi = 0; mi < 4; ++mi)
                    #pragma unroll
                    for (int ni = 0; ni < 4; ++ni)
                        #pragma unroll
                        for (int rg = 0; rg < 4; ++rg)
                            sf[(mi * 16 + g * 4 + rg) * 256 + wn * 64 + ni * 16 + rr] = acc[mi][ni][rg];
            }
            __syncthreads();
            #pragma unroll
            for (int it = 0; it < 8; ++it) {
                int f = t + (it << 9);
                int r = f >> 6, c4 = (f & 63) << 2;
                float4 v = *(const float4*)&sf[r * 256 + c4];
                int gr = m0 + rm * 64 + r, gc = nb0 + c4;
                float* op = out + (size_t)gr * outw + gc;
                if (init) {
                    v.x += bias[biasoff + gc + 0]; v.y += bias[biasoff + gc + 1];
                    v.z += bias[biasoff + gc + 2]; v.w += bias[biasoff + gc + 3];
                } else {
                    float4 o = *(const float4*)op;
                    v.x += o.x; v.y += o.y; v.z += o.z; v.w += o.w;
                }
                if (relu) {
                    v.x = fmaxf(v.x, 0.f); v.y = fmaxf(v.y, 0.f);
                    v.z = fmaxf(v.z, 0.f); v.w = fmaxf(v.w, 0.f);
                }
                *(float4*)op = v;
            }
            __syncthreads();
        }
    } else {
        // tiled bf16 epilogue (A-fragment layout for next GEMM; outw = out_nkt)
        #pragma unroll
        for (int mi = 0; mi < 4; ++mi)
            #pragma unroll
            for (int ni = 0; ni < 4; ++ni) {
                const int c = wn * 64 + ni * 16 + rr;
                float bb = bias[biasoff + nb0 + c];
                #pragma unroll
                for (int rg = 0; rg < 4; ++rg) {
                    float v = acc[mi][ni][rg] + bb;
                    if (relu) v = fmaxf(v, 0.f);
                    int addr = ((wm * 4 + mi) * 4 + wn) * 1024
                             + (ni * 2 + (rr >> 3)) * 128 + (g * 4 + rg) * 8 + (rr & 7);
                    s_mem[addr] = f2bf(v);
                }
            }
        __syncthreads();
        #pragma unroll
        for (int it = 0; it < 8; ++it) {
            int f = t + (it << 9);
            int tl = f >> 7, w8 = f & 127;
            size_t gaddr = ((size_t)(m0 / 16 + (tl >> 2)) * outw + nb0 / 64 + (tl & 3)) * 1024;
            *(float4*)(outt + gaddr + w8 * 8) = *(const float4*)&s_mem[tl * 1024 + w8 * 8];
        }
    }
}

// ---------- distance argmin: 2-phase double-buffered split-bf16 MFMA + margin + rescore ----------
// 128 rows/block, 512 blocks, 8 waves. 128 chunks of 32 codes; DMA(next) issued before compute(cur).
__global__ __launch_bounds__(512, 2) void k_dist(
    float* encq, const unsigned short* __restrict__ ch,
    const unsigned short* __restrict__ cl,
    const float* __restrict__ hsq, const float* __restrict__ cb)
{
    __shared__ __align__(16) unsigned short s_cb[2][16384];  // per buf: hi [0:8192) lo [8192:16384)
    __shared__ __align__(16) float s_erow[EMB];
    __shared__ int s_bi[128], s_need[128];
    __shared__ float s_wb[8]; __shared__ int s_wi[8];

    const int t = threadIdx.x;
    const int lane = t & 63, wv = t >> 6;
    const int g = lane >> 4, rr = lane & 15;
    const int r0 = blockIdx.x * 128;

    // e fragments hi+lo in registers, full K=256 (wave's 16 rows)
    bf16x8 eh[8], el[8];
    {
        const float* ep = encq + (size_t)(r0 + wv * 16 + rr) * EMB + g * 8;
        #pragma unroll
        for (int s = 0; s < 8; ++s) {
            float4 v0 = *(const float4*)(ep + s * 32);
            float4 v1 = *(const float4*)(ep + s * 32 + 4);
            float vv[8] = {v0.x, v0.y, v0.z, v0.w, v1.x, v1.y, v1.z, v1.w};
            bf16x8 a, b;
            #pragma unroll
            for (int j = 0; j < 8; ++j) {
                unsigned short h = f2bf(vv[j]);
                a[j] = (short)h;
                b[j] = (short)f2bf(vv[j] - bf2f(h));
            }
            eh[s] = a; el[s] = b;
        }
    }
    float bst[4] = {-1e30f, -1e30f, -1e30f, -1e30f};
    float sec[4] = {-1e30f, -1e30f, -1e30f, -1e30f};
    int bidx[4] = {0, 0, 0, 0};

    // STAGE(buf, chunk): 32 codes = 8192 ushorts hi (contiguous) + same lo.
    // wave wv copies ushorts [wv*1024, wv*1024+1024) of each.
    #define STAGE_CHUNK(buf, c)                                                     \
        {                                                                           \
            const unsigned short* gh_ = ch + (size_t)(c) * 8192 + wv * 1024;        \
            const unsigned short* gl_ = cl + (size_t)(c) * 8192 + wv * 1024;        \
            _Pragma("unroll")                                                       \
            for (int i_ = 0; i_ < 2; ++i_) {                                        \
                gload16(gh_ + i_ * 512 + lane * 8, &s_cb[buf][wv * 1024 + i_ * 512]); \
                gload16(gl_ + i_ * 512 + lane * 8, &s_cb[buf][8192 + wv * 1024 + i_ * 512]); \
            }                                                                       \
        }

    STAGE_CHUNK(0, 0)
    __syncthreads();                       // drain chunk-0 DMA
    int cur = 0;
    for (int c = 0; c < 128; ++c) {
        if (c < 127) STAGE_CHUNK(cur ^ 1, c + 1)     // issue next-chunk DMA early
        f32x4 acc[2];
        acc[0] = (f32x4){0.f, 0.f, 0.f, 0.f};
        acc[1] = (f32x4){0.f, 0.f, 0.f, 0.f};
        __builtin_amdgcn_s_setprio(1);
        #pragma unroll
        for (int s = 0; s < 8; ++s) {
            const int ktile = s >> 1, kb = ((s & 1) << 2) + g;
            #pragma unroll
            for (int ci = 0; ci < 2; ++ci) {
                const int off = (ci * 4 + ktile) * 1024 + kb * 128 + rr * 8;
                bf16x8 bh = *(const bf16x8*)&s_cb[cur][off];
                bf16x8 bl = *(const bf16x8*)&s_cb[cur][8192 + off];
                acc[ci] = __builtin_amdgcn_mfma_f32_16x16x32_bf16(eh[s], bh, acc[ci], 0, 0, 0);
                acc[ci] = __builtin_amdgcn_mfma_f32_16x16x32_bf16(eh[s], bl, acc[ci], 0, 0, 0);
                acc[ci] = __builtin_amdgcn_mfma_f32_16x16x32_bf16(el[s], bh, acc[ci], 0, 0, 0);
            }
        }
        __builtin_amdgcn_s_setprio(0);
        #pragma unroll
        for (int ci = 0; ci < 2; ++ci) {
            const int code = (c << 5) + (ci << 4) + rr;
            const float hs = hsq[code];
            #pragma unroll
            for (int r2 = 0; r2 < 4; ++r2) {
                float v = acc[ci][r2] - hs;
                if (v > bst[r2]) { sec[r2] = bst[r2]; bst[r2] = v; bidx[r2] = code; }
                else if (v > sec[r2]) sec[r2] = v;
            }
        }
        __syncthreads();                   // buf[cur] consumed; buf[cur^1] DMA drained
        cur ^= 1;
    }
    #undef STAGE_CHUNK

    // intra-wave top-2 merge across the 16 code-lanes
    #pragma unroll
    for (int off = 1; off <= 8; off <<= 1) {
        #pragma unroll
        for (int r2 = 0; r2 < 4; ++r2) {
            float ob = __shfl_xor(bst[r2], off);
            float os2 = __shfl_xor(sec[r2], off);
            int oi = __shfl_xor(bidx[r2], off);
            if (ob > bst[r2] || (ob == bst[r2] && oi < bidx[r2])) {
                sec[r2] = fmaxf(bst[r2], fmaxf(sec[r2], os2));
                bst[r2] = ob; bidx[r2] = oi;
            } else {
                sec[r2] = fmaxf(sec[r2], fmaxf(ob, os2));
            }
        }
    }
    if (rr == 0) {
        #pragma unroll
        for (int r2 = 0; r2 < 4; ++r2) {
            int rl = wv * 16 + g * 4 + r2;
            s_bi[rl] = bidx[r2];
            s_need[rl] = (bst[r2] - sec[r2] <= 0.02f) ? 1 : 0;
        }
    }
    __syncthreads();
    // exact fp32 rescore for margin-flagged rows (uniform branch: s_need is shared)
    for (int r = 0; r < 128; ++r) {
        if (!s_need[r]) continue;
        if (t < 64) ((float4*)s_erow)[t] = ((const float4*)(encq + (size_t)(r0 + r) * EMB))[t];
        __syncthreads();
        float lb = -1e30f; int li = NCODE;
        for (int c = t; c < NCODE; c += 512) {
            const float4* cp = (const float4*)(cb + (size_t)c * EMB);
            float dot = 0.f;
            #pragma unroll 16
            for (int k = 0; k < 64; ++k) {
                float4 ev = ((const float4*)s_erow)[k];
                float4 cv = cp[k];
                dot += ev.x * cv.x + ev.y * cv.y + ev.z * cv.z + ev.w * cv.w;
            }
            float sc = dot - hsq[c];
            if (sc > lb || (sc == lb && c < li)) { lb = sc; li = c; }
        }
        #pragma unroll
        for (int off = 32; off >= 1; off >>= 1) {
            float ov = __shfl_down(lb, off); int oi = __shfl_down(li, off);
            if (ov > lb || (ov == lb && oi < li)) { lb = ov; li = oi; }
        }
        if (lane == 0) { s_wb[wv] = lb; s_wi[wv] = li; }
        __syncthreads();
        if (t == 0) {
            float b = s_wb[0]; int bi = s_wi[0];
            for (int w = 1; w < 8; ++w)
                if (s_wb[w] > b || (s_wb[w] == b && s_wi[w] < bi)) { b = s_wb[w]; bi = s_wi[w]; }
            s_bi[r] = bi;
        }
        __syncthreads();
    }
    __syncthreads();
    // gather: overwrite enc rows with cb[argmin]
    #pragma unroll
    for (int it = 0; it < 16; ++it) {
        int f = t + (it << 9);
        int row = f >> 6, c4 = (f & 63) << 2;
        int bi = s_bi[row];
        *(float4*)(encq + (size_t)(r0 + row) * EMB + c4) =
            *(const float4*)(cb + (size_t)bi * EMB + c4);
    }
}

// ---------- fallback fp32 decoder ----------
__global__ __launch_bounds__(256) void k_dec_fb(
    const float* __restrict__ qz,
    const float* __restrict__ W3, const float* __restrict__ b3,
    const float* __restrict__ W4, const float* __restrict__ b4,
    float* __restrict__ outd) {
    __shared__ float s_q[8][EMB];
    __shared__ float s_h2[8][HID];
    const int t = threadIdx.x;
    const int row0 = blockIdx.x * 8;
    #pragma unroll
    for (int r = 0; r < 8; ++r) s_q[r][t] = qz[(size_t)(row0 + r) * EMB + t];
    __syncthreads();
    for (int gg = 0; gg < 8; ++gg) {
        const int j = (gg << 8) + t;
        float acc[8];
        #pragma unroll
        for (int r = 0; r < 8; ++r) acc[r] = 0.f;
        const float* wp = W3 + j;
        for (int e = 0; e < EMB; e += 4) {
            const float w0 = wp[(size_t)(e + 0) * HID];
            const float w1v = wp[(size_t)(e + 1) * HID];
            const float w2v = wp[(size_t)(e + 2) * HID];
            const float w3v = wp[(size_t)(e + 3) * HID];
            #pragma unroll
            for (int r = 0; r < 8; ++r) {
                const float4 qv = *reinterpret_cast<const float4*>(&s_q[r][e]);
                acc[r] = fmaf(qv.x, w0, acc[r]);
                acc[r] = fmaf(qv.y, w1v, acc[r]);
                acc[r] = fmaf(qv.z, w2v, acc[r]);
                acc[r] = fmaf(qv.w, w3v, acc[r]);
            }
        }
        const float bb = b3[j];
        #pragma unroll
        for (int r = 0; r < 8; ++r) s_h2[r][j] = fmaxf(acc[r] + bb, 0.f);
    }
    __syncthreads();
    float acc4[8][4];
    #pragma unroll
    for (int r = 0; r < 8; ++r)
        #pragma unroll
        for (int ci = 0; ci < 4; ++ci) acc4[r][ci] = 0.f;
    const float* w4p = W4 + t;
    for (int k = 0; k < HID; k += 4) {
        float wv[4][4];
        #pragma unroll
        for (int ki = 0; ki < 4; ++ki)
            #pragma unroll
            for (int ci = 0; ci < 4; ++ci)
                wv[ki][ci] = w4p[(size_t)(k + ki) * IN_DIM + (ci << 8)];
        #pragma unroll
        for (int r = 0; r < 8; ++r) {
            const float4 hv = *reinterpret_cast<const float4*>(&s_h2[r][k]);
            #pragma unroll
            for (int ci = 0; ci < 4; ++ci) {
                acc4[r][ci] = fmaf(hv.x, wv[0][ci], acc4[r][ci]);
                acc4[r][ci] = fmaf(hv.y, wv[1][ci], acc4[r][ci]);
                acc4[r][ci] = fmaf(hv.z, wv[2][ci], acc4[r][ci]);
                acc4[r][ci] = fmaf(hv.w, wv[3][ci], acc4[r][ci]);
            }
        }
    }
    #pragma unroll
    for (int ci = 0; ci < 4; ++ci) {
        const float bb = b4[(ci << 8) + t];
        #pragma unroll
        for (int r = 0; r < 8; ++r)
            outd[(size_t)(row0 + r) * IN_DIM + (ci << 8) + t] = acc4[r][ci] + bb;
    }
}

extern "C" void kernel_launch(void* const* d_in, const int* in_sizes, int n_in,
                              void* d_out, int out_size, void* d_ws, size_t ws_size,
                              hipStream_t stream) {
    const float* x  = (const float*)d_in[0];
    const float* W1 = (const float*)d_in[1];
    const float* b1 = (const float*)d_in[2];
    const float* W2 = (const float*)d_in[3];
    const float* b2 = (const float*)d_in[4];
    const float* cb = (const float*)d_in[5];
    const float* W3 = (const float*)d_in[6];
    const float* b3 = (const float*)d_in[7];
    const float* W4 = (const float*)d_in[8];
    const float* b4 = (const float*)d_in[9];

    float* outq = (float*)d_out;                       // [N,256]
    float* outd = outq + (size_t)N_ROWS * EMB;         // [N,1024]

    // scratch in the decoded-output region (dead before GEMM4 writes it)
    unsigned short* ou = (unsigned short*)outd;
    unsigned short* W1Th = ou;                         // 2M ushort
    unsigned short* W1Tl = ou + 2097152;               // 2M
    unsigned short* W2Th = ou + 4194304;               // 512K
    unsigned short* W2Tl = ou + 4718592;               // 512K
    unsigned short* cbh  = ou + 5242880;               // 1M
    unsigned short* cbl  = ou + 6291456;               // 1M
    float* halfsq = outd + 3670016;                    // 4K floats (after cbl)
    float* hbuf   = outd + 4194304;                    // N*512 fp32 (128 MiB)
    float* enc    = outq;                              // N*256 fp32, consumed by k_dist

    // d_ws: W3T (1MB) + W4T (4MB) + h2t strip (tiled bf16, 64MB, one 16384-row strip)
    const bool fastdec = ws_size >= (size_t)72351744;
    unsigned short* W3Th = (unsigned short*)d_ws;
    unsigned short* W4Th = W3Th + 524288;
    unsigned short* h2t  = (unsigned short*)((char*)d_ws + 5242880);

    // prep: weight/codebook conversion
    k_conv_w<1><<<dim3(128, 16), 256, 0, stream>>>(W1, W1Th, W1Tl, HID, 16);
    k_conv_w<1><<<dim3(16, 32), 256, 0, stream>>>(W2, W2Th, W2Tl, EMB, 32);
    k_conv_cb<<<256, 256, 0, stream>>>(cb, cbh, cbl, halfsq);
    if (fastdec) {
        k_conv_w<0><<<dim3(128, 4), 256, 0, stream>>>(W3, W3Th, nullptr, HID, 4);
        k_conv_w<0><<<dim3(64, 32), 256, 0, stream>>>(W4, W4Th, nullptr, IN_DIM, 32);
    }
    // encoder: split-bf16, hidden quarters (h fp32 strip in outd)
    for (int q = 0; q < 4; ++q) {
        k_layer2<1, 0, 0><<<dim3(512, 2), 512, 0, stream>>>(
            x, nullptr, 0, IN_DIM, IN_DIM,
            W1Th + (size_t)q * 524288, W1Tl + (size_t)q * 524288, 16,
            b1, q * 512, hbuf, nullptr, 512, 1, 1);
        k_layer2<1, 0, 0><<<dim3(512, 1), 512, 0, stream>>>(
            hbuf, nullptr, 0, 512, 512,
            W2Th + (size_t)q * 8192, W2Tl + (size_t)q * 8192, 32,
            b2, 0, enc, nullptr, EMB, 0, q == 0);
    }
    // nearest-code + gather (writes quantized output in place)
    k_dist<<<512, 512, 0, stream>>>(enc, cbh, cbl, halfsq, cb);
    // decoder: 4 m-strips of 16384 rows; full-width h2 per strip, single-pass GEMM4
    if (fastdec) {
        for (int s = 0; s < 4; ++s) {
            const size_t roff = (size_t)s * 16384;
            // GEMM3: h2 strip = relu(q_strip @ W3 + b3) -> tiled bf16 (out_nkt=32)
            k_layer2<0, 0, 1><<<dim3(128, 8), 512, 0, stream>>>(
                outq + roff * EMB, nullptr, 0, EMB, EMB,
                W3Th, nullptr, 4,
                b3, 0, nullptr, h2t, 32, 1, 0);
            // GEMM4: outd strip = h2 strip @ W4 + b4 (single pass, K=2048)
            k_layer2<0, 1, 0><<<dim3(128, 4), 512, 0, stream>>>(
                nullptr, h2t, 32, 0, HID,
                W4Th, nullptr, 32,
                b4, 0, outd + roff * IN_DIM, nullptr, IN_DIM, 0, 1);
        }
    } else {
        k_dec_fb<<<N_ROWS / 8, 256, 0, stream>>>(outq, W3, b3, W4, b4, outd);
    }
}

// Round 8
// 2734.848 us; speedup vs baseline: 6.0366x; 1.2064x over previous
//
#include <hip/hip_runtime.h>

#define N_ROWS 65536
#define IN_DIM 1024
#define HID    2048
#define EMB    256
#define NCODE  4096

typedef __attribute__((ext_vector_type(8))) short bf16x8;
typedef __attribute__((ext_vector_type(4))) float f32x4;

__device__ __forceinline__ unsigned short f2bf(float v) {
    unsigned u = __float_as_uint(v);
    u += 0x7FFFu + ((u >> 16) & 1u);
    return (unsigned short)(u >> 16);
}
__device__ __forceinline__ float bf2f(unsigned short h) {
    return __uint_as_float(((unsigned)h) << 16);
}
// async global->LDS 16B: per-lane global src, wave-uniform LDS base (+lane*16 by HW)
__device__ __forceinline__ void gload16(const unsigned short* g, unsigned short* l) {
    __builtin_amdgcn_global_load_lds(
        (const __attribute__((address_space(1))) unsigned int*)g,
        (__attribute__((address_space(3))) unsigned int*)l, 16, 0, 0);
}

// ---------- weight pre-convert (+transpose) into tiled fragment layout ----------
template<int SPLIT>
__global__ __launch_bounds__(256) void k_conv_w(
    const float* __restrict__ src, unsigned short* __restrict__ dh,
    unsigned short* __restrict__ dl, int NC, int nkt)
{
    const int t = threadIdx.x;
    const int nt = blockIdx.x, kt = blockIdx.y;
    const int kk = t >> 2, j4 = (t & 3) << 2;
    const int k0 = kt << 6, n0 = nt << 4;
    float4 v = *(const float4*)(src + (size_t)(k0 + kk) * NC + n0 + j4);
    size_t tb = ((size_t)nt * nkt + kt) * 1024 + ((kk >> 3) * 128) + (kk & 7);
    float vv[4] = {v.x, v.y, v.z, v.w};
    #pragma unroll
    for (int j = 0; j < 4; ++j) {
        unsigned short h = f2bf(vv[j]);
        dh[tb + (size_t)(j4 + j) * 8] = h;
        if (SPLIT) dl[tb + (size_t)(j4 + j) * 8] = f2bf(vv[j] - bf2f(h));
    }
}

// ---------- codebook convert (tiled bf16 hi+lo) + 0.5*||c||^2 ----------
__global__ __launch_bounds__(256) void k_conv_cb(
    const float* __restrict__ cb, unsigned short* __restrict__ ch,
    unsigned short* __restrict__ cl_, float* __restrict__ halfsq)
{
    const int t = threadIdx.x;
    const int ct = blockIdx.x;
    const int cl = t >> 4, f = t & 15;
    const int code = (ct << 4) + cl;
    float ssq = 0.f;
    #pragma unroll
    for (int it = 0; it < 4; ++it) {
        const int k4 = (f << 2) + (it << 6);
        float4 v = *(const float4*)(cb + (size_t)code * EMB + k4);
        ssq += v.x * v.x + v.y * v.y + v.z * v.z + v.w * v.w;
        size_t tb = ((size_t)(ct * 4 + (k4 >> 6))) * 1024 + ((k4 >> 3) & 7) * 128 + cl * 8 + (k4 & 7);
        ushort4 h = { f2bf(v.x), f2bf(v.y), f2bf(v.z), f2bf(v.w) };
        *(ushort4*)&ch[tb] = h;
        ushort4 lo = { f2bf(v.x - bf2f(h.x)), f2bf(v.y - bf2f(h.y)),
                       f2bf(v.z - bf2f(h.z)), f2bf(v.w - bf2f(h.w)) };
        *(ushort4*)&cl_[tb] = lo;
    }
    #pragma unroll
    for (int off = 1; off <= 8; off <<= 1) ssq += __shfl_xor(ssq, off);
    if (f == 0) halfsq[code] = 0.5f * ssq;
}

// ---------- MFMA layer v2: BM=128, BN=256, BK=64, 512 thr (8 waves 2x4) ----------
template<int SPLIT, int AFMT, int OUTT>
__global__ __launch_bounds__(512, 2) void k_layer2(
    const float* __restrict__ A, const unsigned short* __restrict__ At, int a_nkt,
    int lda, int K,
    const unsigned short* __restrict__ Bh, const unsigned short* __restrict__ Bl,
    int b_nkt, const float* __restrict__ bias, int biasoff,
    float* __restrict__ out, unsigned short* __restrict__ outt,
    int outw, int relu, int init)
{
    constexpr int AL = 8192;
    constexpr int BH = SPLIT ? 16384 : 8192;
    constexpr int BL = SPLIT ? 32768 : 8192;
    __shared__ __align__(16) unsigned short s_mem[SPLIT ? 49152 : 32768];

    const int t = threadIdx.x;
    const int m0 = blockIdx.x * 128;
    const int nb0 = blockIdx.y * 256;
    const int lane = t & 63, wv = t >> 6;
    const int wm = wv >> 2, wn = wv & 3;
    const int g = lane >> 4, rr = lane & 15;

    f32x4 acc[4][4];
    #pragma unroll
    for (int mi = 0; mi < 4; ++mi)
        #pragma unroll
        for (int ni = 0; ni < 4; ++ni) acc[mi][ni] = (f32x4){0.f, 0.f, 0.f, 0.f};

    for (int kc = 0; kc < K; kc += 64) {
        const int ktile = kc >> 6;
        #pragma unroll
        for (int jj = 0; jj < 2; ++jj) {
            const int j = wv * 2 + jj;
            const size_t gt = ((size_t)(nb0 / 16 + j) * b_nkt + ktile) * 1024;
            #pragma unroll
            for (int half = 0; half < 2; ++half) {
                gload16(Bh + gt + half * 512 + lane * 8,
                        &s_mem[BH + j * 1024 + half * 512]);
                if (SPLIT)
                    gload16(Bl + gt + half * 512 + lane * 8,
                            &s_mem[BL + j * 1024 + half * 512]);
            }
        }
        if (AFMT == 0) {
            #pragma unroll
            for (int it = 0; it < 4; ++it) {
                int f = t + (it << 9);
                int r = f >> 4, k4 = (f & 15) << 2;
                float4 v = *(const float4*)(A + (size_t)(m0 + r) * lda + kc + k4);
                int mt = r >> 4, rl = r & 15, kb = k4 >> 3, e = k4 & 7;
                int addr = mt * 1024 + kb * 128 + ((rl ^ kb) << 3) + e;
                ushort4 hi, lo;
                hi.x = f2bf(v.x); hi.y = f2bf(v.y); hi.z = f2bf(v.z); hi.w = f2bf(v.w);
                *(ushort4*)&s_mem[addr] = hi;
                if (SPLIT) {
                    lo.x = f2bf(v.x - bf2f(hi.x)); lo.y = f2bf(v.y - bf2f(hi.y));
                    lo.z = f2bf(v.z - bf2f(hi.z)); lo.w = f2bf(v.w - bf2f(hi.w));
                    *(ushort4*)&s_mem[AL + addr] = lo;
                }
            }
        } else {
            const size_t gt = ((size_t)(m0 / 16 + wv) * a_nkt + ktile) * 1024;
            #pragma unroll
            for (int half = 0; half < 2; ++half)
                gload16(At + gt + half * 512 + lane * 8,
                        &s_mem[wv * 1024 + half * 512]);
        }
        __syncthreads();
        __builtin_amdgcn_s_setprio(1);
        #pragma unroll
        for (int s = 0; s < 2; ++s) {
            const int kb = (s << 2) + g;
            bf16x8 a_h[4], a_l[4], b_h[4], b_l[4];
            #pragma unroll
            for (int i = 0; i < 4; ++i) {
                int arow = (AFMT == 0) ? (((rr ^ kb) & 15) << 3) : (rr << 3);
                int aaddr = (wm * 4 + i) * 1024 + kb * 128 + arow;
                a_h[i] = *(const bf16x8*)&s_mem[aaddr];
                if (SPLIT) a_l[i] = *(const bf16x8*)&s_mem[AL + aaddr];
                int baddr = (wn * 4 + i) * 1024 + kb * 128 + (rr << 3);
                b_h[i] = *(const bf16x8*)&s_mem[BH + baddr];
                if (SPLIT) b_l[i] = *(const bf16x8*)&s_mem[BL + baddr];
            }
            #pragma unroll
            for (int mi = 0; mi < 4; ++mi)
                #pragma unroll
                for (int ni = 0; ni < 4; ++ni) {
                    acc[mi][ni] = __builtin_amdgcn_mfma_f32_16x16x32_bf16(a_h[mi], b_h[ni], acc[mi][ni], 0, 0, 0);
                    if (SPLIT) {
                        acc[mi][ni] = __builtin_amdgcn_mfma_f32_16x16x32_bf16(a_h[mi], b_l[ni], acc[mi][ni], 0, 0, 0);
                        acc[mi][ni] = __builtin_amdgcn_mfma_f32_16x16x32_bf16(a_l[mi], b_h[ni], acc[mi][ni], 0, 0, 0);
                    }
                }
        }
        __builtin_amdgcn_s_setprio(0);
        __syncthreads();
    }

    if (OUTT == 0) {
        float* sf = (float*)s_mem;
        for (int rm = 0; rm < 2; ++rm) {
            if (wm == rm) {
                #pragma unroll
                for (int mi = 0; mi < 4; ++mi)
                    #pragma unroll
                    for (int ni = 0; ni < 4; ++ni)
                        #pragma unroll
                        for (int rg = 0; rg < 4; ++rg)
                            sf[(mi * 16 + g * 4 + rg) * 256 + wn * 64 + ni * 16 + rr] = acc[mi][ni][rg];
            }
            __syncthreads();
            #pragma unroll
            for (int it = 0; it < 8; ++it) {
                int f = t + (it << 9);
                int r = f >> 6, c4 = (f & 63) << 2;
                float4 v = *(const float4*)&sf[r * 256 + c4];
                int gr = m0 + rm * 64 + r, gc = nb0 + c4;
                float* op = out + (size_t)gr * outw + gc;
                if (init) {
                    v.x += bias[biasoff + gc + 0]; v.y += bias[biasoff + gc + 1];
                    v.z += bias[biasoff + gc + 2]; v.w += bias[biasoff + gc + 3];
                } else {
                    float4 o = *(const float4*)op;
                    v.x += o.x; v.y += o.y; v.z += o.z; v.w += o.w;
                }
                if (relu) {
                    v.x = fmaxf(v.x, 0.f); v.y = fmaxf(v.y, 0.f);
                    v.z = fmaxf(v.z, 0.f); v.w = fmaxf(v.w, 0.f);
                }
                *(float4*)op = v;
            }
            __syncthreads();
        }
    } else {
        #pragma unroll
        for (int mi = 0; mi < 4; ++mi)
            #pragma unroll
            for (int ni = 0; ni < 4; ++ni) {
                const int c = wn * 64 + ni * 16 + rr;
                float bb = bias[biasoff + nb0 + c];
                #pragma unroll
                for (int rg = 0; rg < 4; ++rg) {
                    float v = acc[mi][ni][rg] + bb;
                    if (relu) v = fmaxf(v, 0.f);
                    int addr = ((wm * 4 + mi) * 4 + wn) * 1024
                             + (ni * 2 + (rr >> 3)) * 128 + (g * 4 + rg) * 8 + (rr & 7);
                    s_mem[addr] = f2bf(v);
                }
            }
        __syncthreads();
        #pragma unroll
        for (int it = 0; it < 8; ++it) {
            int f = t + (it << 9);
            int tl = f >> 7, w8 = f & 127;
            size_t gaddr = ((size_t)(m0 / 16 + (tl >> 2)) * outw + nb0 / 64 + (tl & 3)) * 1024;
            *(float4*)(outt + gaddr + w8 * 8) = *(const float4*)&s_mem[tl * 1024 + w8 * 8];
        }
    }
}

// ---------- distance argmin v4: dbuf DMA + counted vmcnt + 6 independent MFMA chains ----------
// 128 rows/block, 512 blocks, 8 waves, 128 chunks of 32 codes. Top-2 indices tracked in scan
// (split-bf16 scores); exact fp32 rescore of both candidates per row at the end.
__global__ __launch_bounds__(512, 4) void k_dist(
    float* encq, const unsigned short* __restrict__ ch,
    const unsigned short* __restrict__ cl,
    const float* __restrict__ hsq, const float* __restrict__ cb)
{
    __shared__ __align__(16) unsigned short s_cb[2][16384];  // per buf: hi [0:8192) lo [8192:16384)
    __shared__ int s_c1[128], s_c2[128];

    const int t = threadIdx.x;
    const int lane = t & 63, wv = t >> 6;
    const int g = lane >> 4, rr = lane & 15;
    const int r0 = blockIdx.x * 128;

    // e fragments hi+lo in registers, full K=256 (wave's 16 rows)
    bf16x8 eh[8], el[8];
    {
        const float* ep = encq + (size_t)(r0 + wv * 16 + rr) * EMB + g * 8;
        #pragma unroll
        for (int s = 0; s < 8; ++s) {
            float4 v0 = *(const float4*)(ep + s * 32);
            float4 v1 = *(const float4*)(ep + s * 32 + 4);
            float vv[8] = {v0.x, v0.y, v0.z, v0.w, v1.x, v1.y, v1.z, v1.w};
            bf16x8 a, b;
            #pragma unroll
            for (int j = 0; j < 8; ++j) {
                unsigned short h = f2bf(vv[j]);
                a[j] = (short)h;
                b[j] = (short)f2bf(vv[j] - bf2f(h));
            }
            eh[s] = a; el[s] = b;
        }
    }
    float b1v[4], b2v[4]; int i1v[4], i2v[4];
    #pragma unroll
    for (int r2 = 0; r2 < 4; ++r2) { b1v[r2] = -1e30f; b2v[r2] = -1e30f; i1v[r2] = 0; i2v[r2] = 0; }

    // stage: 32 codes = 8192 ushorts hi + 8192 lo; wave wv copies its 1024-ushort slice of each
    #define STAGE(buf, c)                                                              \
        {                                                                              \
            const unsigned short* gh_ = ch + (size_t)(c) * 8192 + wv * 1024;           \
            const unsigned short* gl_ = cl + (size_t)(c) * 8192 + wv * 1024;           \
            _Pragma("unroll")                                                          \
            for (int i_ = 0; i_ < 2; ++i_) {                                           \
                gload16(gh_ + i_ * 512 + lane * 8, &s_cb[buf][wv * 1024 + i_ * 512]);  \
                gload16(gl_ + i_ * 512 + lane * 8, &s_cb[buf][8192 + wv * 1024 + i_ * 512]); \
            }                                                                          \
        }

    // compute one 32-code chunk from buf `cur` for chunk index c, hsq value hv_ (lanes 0..31 hold codes c*32+lane)
    #define COMPUTE(cur, c, hv_)                                                       \
        {                                                                              \
            f32x4 ahh[2], ahl[2], alh[2];                                              \
            _Pragma("unroll")                                                          \
            for (int ci = 0; ci < 2; ++ci) {                                           \
                ahh[ci] = (f32x4){0.f, 0.f, 0.f, 0.f};                                 \
                ahl[ci] = (f32x4){0.f, 0.f, 0.f, 0.f};                                 \
                alh[ci] = (f32x4){0.f, 0.f, 0.f, 0.f};                                 \
            }                                                                          \
            __builtin_amdgcn_s_setprio(1);                                             \
            _Pragma("unroll")                                                          \
            for (int s = 0; s < 8; ++s) {                                              \
                const int ktile = s >> 1, kb = ((s & 1) << 2) + g;                     \
                _Pragma("unroll")                                                      \
                for (int ci = 0; ci < 2; ++ci) {                                       \
                    const int off = (ci * 4 + ktile) * 1024 + kb * 128 + rr * 8;       \
                    bf16x8 bh = *(const bf16x8*)&s_cb[cur][off];                       \
                    bf16x8 bl = *(const bf16x8*)&s_cb[cur][8192 + off];                \
                    ahh[ci] = __builtin_amdgcn_mfma_f32_16x16x32_bf16(eh[s], bh, ahh[ci], 0, 0, 0); \
                    ahl[ci] = __builtin_amdgcn_mfma_f32_16x16x32_bf16(eh[s], bl, ahl[ci], 0, 0, 0); \
                    alh[ci] = __builtin_amdgcn_mfma_f32_16x16x32_bf16(el[s], bh, alh[ci], 0, 0, 0); \
                }                                                                      \
            }                                                                          \
            __builtin_amdgcn_s_setprio(0);                                             \
            _Pragma("unroll")                                                          \
            for (int ci = 0; ci < 2; ++ci) {                                           \
                f32x4 av = ahh[ci] + ahl[ci] + alh[ci];                                \
                const int code = ((c) << 5) + (ci << 4) + rr;                          \
                const float hs = __shfl(hv_, ci * 16 + rr);                            \
                _Pragma("unroll")                                                      \
                for (int r2 = 0; r2 < 4; ++r2) {                                       \
                    float v = av[r2] - hs;                                             \
                    bool bt1 = (v > b1v[r2]) || (v == b1v[r2] && code < i1v[r2]);      \
                    bool bt2 = (v > b2v[r2]) || (v == b2v[r2] && code < i2v[r2]);      \
                    if (bt1) { b2v[r2] = b1v[r2]; i2v[r2] = i1v[r2]; b1v[r2] = v; i1v[r2] = code; } \
                    else if (bt2) { b2v[r2] = v; i2v[r2] = code; }                     \
                }                                                                      \
            }                                                                          \
        }

    STAGE(0, 0)
    int cur = 0;
    for (int c = 0; c < 127; ++c) {
        STAGE(cur ^ 1, c + 1)                         // 4 loads in flight across barrier
        float hv_ = hsq[(c << 5) + (lane & 31)];      // +1 load (current chunk's norms)
        asm volatile("s_waitcnt vmcnt(5)" ::: "memory");   // drain stage(c); keep 4+1 newest
        __builtin_amdgcn_s_barrier();
        __builtin_amdgcn_sched_barrier(0);
        COMPUTE(cur, c, hv_)
        asm volatile("" ::: "memory");
        __builtin_amdgcn_s_barrier();                 // buf[cur] consumed by all waves
        cur ^= 1;
    }
    {
        float hv_ = hsq[(127 << 5) + (lane & 31)];
        asm volatile("s_waitcnt vmcnt(0)" ::: "memory");
        __builtin_amdgcn_s_barrier();
        __builtin_amdgcn_sched_barrier(0);
        COMPUTE(cur, 127, hv_)
    }
    #undef STAGE
    #undef COMPUTE

    // merge top-2 across the 16 code-lanes (xor over lane bits 0..3)
    #pragma unroll
    for (int off = 1; off <= 8; off <<= 1) {
        #pragma unroll
        for (int r2 = 0; r2 < 4; ++r2) {
            float ob1 = __shfl_xor(b1v[r2], off), ob2 = __shfl_xor(b2v[r2], off);
            int oi1 = __shfl_xor(i1v[r2], off), oi2 = __shfl_xor(i2v[r2], off);
            bool ofirst = (ob1 > b1v[r2]) || (ob1 == b1v[r2] && oi1 < i1v[r2]);
            if (ofirst) {
                bool mysec = (b1v[r2] > ob2) || (b1v[r2] == ob2 && i1v[r2] < oi2);
                b2v[r2] = mysec ? b1v[r2] : ob2; i2v[r2] = mysec ? i1v[r2] : oi2;
                b1v[r2] = ob1; i1v[r2] = oi1;
            } else {
                bool osec = (ob1 > b2v[r2]) || (ob1 == b2v[r2] && oi1 < i2v[r2]);
                b2v[r2] = osec ? ob1 : b2v[r2]; i2v[r2] = osec ? oi1 : i2v[r2];
            }
        }
    }
    if (rr == 0) {
        #pragma unroll
        for (int r2 = 0; r2 < 4; ++r2) {
            int rl = wv * 16 + g * 4 + r2;
            s_c1[rl] = i1v[r2]; s_c2[rl] = i2v[r2];
        }
    }
    __syncthreads();

    // exact fp32 rescore of both candidates, wave-parallel (wave wv owns rows wv*16..+15)
    for (int rloc = 0; rloc < 16; ++rloc) {
        const int row = wv * 16 + rloc;
        const int c1 = s_c1[row], c2 = s_c2[row];
        float4 ev = *(const float4*)(encq + (size_t)(r0 + row) * EMB + lane * 4);
        float4 v1 = *(const float4*)(cb + (size_t)c1 * EMB + lane * 4);
        float4 v2 = *(const float4*)(cb + (size_t)c2 * EMB + lane * 4);
        float d1 = ev.x * v1.x + ev.y * v1.y + ev.z * v1.z + ev.w * v1.w;
        float d2 = ev.x * v2.x + ev.y * v2.y + ev.z * v2.z + ev.w * v2.w;
        #pragma unroll
        for (int off = 1; off <= 32; off <<= 1) {
            d1 += __shfl_xor(d1, off);
            d2 += __shfl_xor(d2, off);
        }
        if (lane == 0) {
            float s1 = d1 - hsq[c1], s2 = d2 - hsq[c2];
            bool keep1 = (s1 > s2) || (s1 == s2 && c1 < c2);
            s_c1[row] = keep1 ? c1 : c2;
        }
    }
    __syncthreads();
    // gather: overwrite enc rows with cb[argmin]
    #pragma unroll
    for (int it = 0; it < 16; ++it) {
        int f = t + (it << 9);
        int row = f >> 6, c4 = (f & 63) << 2;
        int bi = s_c1[row];
        *(float4*)(encq + (size_t)(r0 + row) * EMB + c4) =
            *(const float4*)(cb + (size_t)bi * EMB + c4);
    }
}

// ---------- fallback fp32 decoder ----------
__global__ __launch_bounds__(256) void k_dec_fb(
    const float* __restrict__ qz,
    const float* __restrict__ W3, const float* __restrict__ b3,
    const float* __restrict__ W4, const float* __restrict__ b4,
    float* __restrict__ outd) {
    __shared__ float s_q[8][EMB];
    __shared__ float s_h2[8][HID];
    const int t = threadIdx.x;
    const int row0 = blockIdx.x * 8;
    #pragma unroll
    for (int r = 0; r < 8; ++r) s_q[r][t] = qz[(size_t)(row0 + r) * EMB + t];
    __syncthreads();
    for (int gg = 0; gg < 8; ++gg) {
        const int j = (gg << 8) + t;
        float acc[8];
        #pragma unroll
        for (int r = 0; r < 8; ++r) acc[r] = 0.f;
        const float* wp = W3 + j;
        for (int e = 0; e < EMB; e += 4) {
            const float w0 = wp[(size_t)(e + 0) * HID];
            const float w1v = wp[(size_t)(e + 1) * HID];
            const float w2v = wp[(size_t)(e + 2) * HID];
            const float w3v = wp[(size_t)(e + 3) * HID];
            #pragma unroll
            for (int r = 0; r < 8; ++r) {
                const float4 qv = *reinterpret_cast<const float4*>(&s_q[r][e]);
                acc[r] = fmaf(qv.x, w0, acc[r]);
                acc[r] = fmaf(qv.y, w1v, acc[r]);
                acc[r] = fmaf(qv.z, w2v, acc[r]);
                acc[r] = fmaf(qv.w, w3v, acc[r]);
            }
        }
        const float bb = b3[j];
        #pragma unroll
        for (int r = 0; r < 8; ++r) s_h2[r][j] = fmaxf(acc[r] + bb, 0.f);
    }
    __syncthreads();
    float acc4[8][4];
    #pragma unroll
    for (int r = 0; r < 8; ++r)
        #pragma unroll
        for (int ci = 0; ci < 4; ++ci) acc4[r][ci] = 0.f;
    const float* w4p = W4 + t;
    for (int k = 0; k < HID; k += 4) {
        float wv[4][4];
        #pragma unroll
        for (int ki = 0; ki < 4; ++ki)
            #pragma unroll
            for (int ci = 0; ci < 4; ++ci)
                wv[ki][ci] = w4p[(size_t)(k + ki) * IN_DIM + (ci << 8)];
        #pragma unroll
        for (int r = 0; r < 8; ++r) {
            const float4 hv = *reinterpret_cast<const float4*>(&s_h2[r][k]);
            #pragma unroll
            for (int ci = 0; ci < 4; ++ci) {
                acc4[r][ci] = fmaf(hv.x, wv[0][ci], acc4[r][ci]);
                acc4[r][ci] = fmaf(hv.y, wv[1][ci], acc4[r][ci]);
                acc4[r][ci] = fmaf(hv.z, wv[2][ci], acc4[r][ci]);
                acc4[r][ci] = fmaf(hv.w, wv[3][ci], acc4[r][ci]);
            }
        }
    }
    #pragma unroll
    for (int ci = 0; ci < 4; ++ci) {
        const float bb = b4[(ci << 8) + t];
        #pragma unroll
        for (int r = 0; r < 8; ++r)
            outd[(size_t)(row0 + r) * IN_DIM + (ci << 8) + t] = acc4[r][ci] + bb;
    }
}

extern "C" void kernel_launch(void* const* d_in, const int* in_sizes, int n_in,
                              void* d_out, int out_size, void* d_ws, size_t ws_size,
                              hipStream_t stream) {
    const float* x  = (const float*)d_in[0];
    const float* W1 = (const float*)d_in[1];
    const float* b1 = (const float*)d_in[2];
    const float* W2 = (const float*)d_in[3];
    const float* b2 = (const float*)d_in[4];
    const float* cb = (const float*)d_in[5];
    const float* W3 = (const float*)d_in[6];
    const float* b3 = (const float*)d_in[7];
    const float* W4 = (const float*)d_in[8];
    const float* b4 = (const float*)d_in[9];

    float* outq = (float*)d_out;                       // [N,256]
    float* outd = outq + (size_t)N_ROWS * EMB;         // [N,1024]

    // scratch in the decoded-output region (dead before GEMM4 writes it)
    unsigned short* ou = (unsigned short*)outd;
    unsigned short* W1Th = ou;                         // 2M ushort
    unsigned short* W1Tl = ou + 2097152;               // 2M
    unsigned short* W2Th = ou + 4194304;               // 512K
    unsigned short* W2Tl = ou + 4718592;               // 512K
    unsigned short* cbh  = ou + 5242880;               // 1M
    unsigned short* cbl  = ou + 6291456;               // 1M
    float* halfsq = outd + 3670016;                    // 4K floats (after cbl)
    float* hbuf   = outd + 4194304;                    // N*512 fp32 (128 MiB)
    float* enc    = outq;                              // N*256 fp32, consumed by k_dist

    // d_ws: W3T (1MB) + W4T (4MB) + h2t strip (tiled bf16, 64MB, one 16384-row strip)
    const bool fastdec = ws_size >= (size_t)72351744;
    unsigned short* W3Th = (unsigned short*)d_ws;
    unsigned short* W4Th = W3Th + 524288;
    unsigned short* h2t  = (unsigned short*)((char*)d_ws + 5242880);

    // prep: weight/codebook conversion
    k_conv_w<1><<<dim3(128, 16), 256, 0, stream>>>(W1, W1Th, W1Tl, HID, 16);
    k_conv_w<1><<<dim3(16, 32), 256, 0, stream>>>(W2, W2Th, W2Tl, EMB, 32);
    k_conv_cb<<<256, 256, 0, stream>>>(cb, cbh, cbl, halfsq);
    if (fastdec) {
        k_conv_w<0><<<dim3(128, 4), 256, 0, stream>>>(W3, W3Th, nullptr, HID, 4);
        k_conv_w<0><<<dim3(64, 32), 256, 0, stream>>>(W4, W4Th, nullptr, IN_DIM, 32);
    }
    // encoder: split-bf16, hidden quarters (h fp32 strip in outd)
    for (int q = 0; q < 4; ++q) {
        k_layer2<1, 0, 0><<<dim3(512, 2), 512, 0, stream>>>(
            x, nullptr, 0, IN_DIM, IN_DIM,
            W1Th + (size_t)q * 524288, W1Tl + (size_t)q * 524288, 16,
            b1, q * 512, hbuf, nullptr, 512, 1, 1);
        k_layer2<1, 0, 0><<<dim3(512, 1), 512, 0, stream>>>(
            hbuf, nullptr, 0, 512, 512,
            W2Th + (size_t)q * 8192, W2Tl + (size_t)q * 8192, 32,
            b2, 0, enc, nullptr, EMB, 0, q == 0);
    }
    // nearest-code + gather (writes quantized output in place)
    k_dist<<<512, 512, 0, stream>>>(enc, cbh, cbl, halfsq, cb);
    // decoder: 4 m-strips of 16384 rows; full-width h2 per strip, single-pass GEMM4
    if (fastdec) {
        for (int s = 0; s < 4; ++s) {
            const size_t roff = (size_t)s * 16384;
            k_layer2<0, 0, 1><<<dim3(128, 8), 512, 0, stream>>>(
                outq + roff * EMB, nullptr, 0, EMB, EMB,
                W3Th, nullptr, 4,
                b3, 0, nullptr, h2t, 32, 1, 0);
            k_layer2<0, 1, 0><<<dim3(128, 4), 512, 0, stream>>>(
                nullptr, h2t, 32, 0, HID,
                W4Th, nullptr, 32,
                b4, 0, outd + roff * IN_DIM, nullptr, IN_DIM, 0, 1);
        }
    } else {
        k_dec_fb<<<N_ROWS / 8, 256, 0, stream>>>(outq, W3, b3, W4, b4, outd);
    }
}